// Round 11
// baseline (2444.765 us; speedup 1.0000x reference)
//
#include <hip/hip_runtime.h>
#include <hip/hip_cooperative_groups.h>

namespace cg = cooperative_groups;

typedef unsigned short u16;
typedef __bf16 bf16x8 __attribute__((ext_vector_type(8)));
typedef float f32x4 __attribute__((ext_vector_type(4)));

#define NB 32          // batch
#define NS 512         // seq
#define NH 768         // hidden
#define NK 4           // heads
#define NBS 16384      // B*S
#define H3 2304        // 3H
#define HH 589824      // 768*768

__device__ inline float bf2f(u16 u) {
    unsigned x = ((unsigned)u) << 16;
    return __builtin_bit_cast(float, x);
}
__device__ inline u16 f2bf(float f) {
    unsigned u = __builtin_bit_cast(unsigned, f);
    u += 0x7fffu + ((u >> 16) & 1u);
    return (u16)(u >> 16);
}
// fast tanh: 1 - 2*rcp(exp(2x)+1). ~5 VALU vs ~20+ for libm tanhf. err ~1e-6.
__device__ inline float tanh_fast(float x) {
    float e = __expf(2.f * x);
    return 1.f - 2.f * __builtin_amdgcn_rcpf(e + 1.f);
}
__device__ inline float sig_fast(float x) {
    return __builtin_amdgcn_rcpf(1.f + __expf(-x));
}
// async global->LDS, 16B/lane; LDS dst = wave-uniform base + lane*16 (m97 recipe).
__device__ inline void gld16(const u16* g, u16* l) {
    __builtin_amdgcn_global_load_lds(
        (const __attribute__((address_space(1))) unsigned int*)g,
        (__attribute__((address_space(3))) unsigned int*)l, 16, 0, 0);
}

// ---------------------------------------------------------------------------
// Workspace layout: see R9 (unchanged).
//  combB @ 9,437,184 | W_ht @ 9,449,472 | scores @ 9,842,688
//  q_f32 @ 10,104,832 | hT @ 10,203,136 | xT @ 10,301,440
//  sx @ 10,498,048 | sh @ 10,792,960 | combTH @ 11,087,872 | combTL @ 15,806,464
//  TP @ 20,525,056 (NSTORE x 25,165,824 bf16) | textH @ 121,188,352
//  prep scratch overlaid on TP: WsTH/WsTL/pwH/pwL.
//
// R10: the 3-hop chain (wht2 -> score_pass -> softmax -> gru -> gate, 15
// serial launches) collapses into ONE cooperative kernel with grid.sync
// between phases. Accounting showed ~250 us of inter-launch serialization
// (hop kernels' compute sums to ~150 us but the chains cost ~400 us wall).
// 1024 blocks x 256 thr, __launch_bounds__(256,4) + 32 KB LDS => 4 blocks/CU
// co-resident. Return-code-checked; falls back to the R9 sequence on error.
// ---------------------------------------------------------------------------

// P: one-time prep. grid up to 17968 (sections gated).
__global__ void prep_kernel(const float* __restrict__ WsW, const float* __restrict__ pwb,
                            const float* __restrict__ Wsb, float* __restrict__ combB,
                            const float* __restrict__ question,
                            float* __restrict__ q_f32, float* __restrict__ hT,
                            float* __restrict__ sx, float* __restrict__ sh,
                            const float* __restrict__ Web, float* __restrict__ scores,
                            const float* __restrict__ pwW,
                            u16* __restrict__ WsTH, u16* __restrict__ WsTL,
                            u16* __restrict__ pwH, u16* __restrict__ pwL,
                            const float* __restrict__ text, u16* __restrict__ textH,
                            int tier, int splitText)
{
    int bid = blockIdx.x, t = threadIdx.x;
    if (bid < 48) {
        int idx = bid * 64 + (t >> 2);      // 0..3071
        int ph = t & 3;
        int k = idx / NH, j = idx % NH;
        const float* W = WsW + (long)k * HH + j;
        const float* pb = pwb + k * NH;
        float acc = 0.f;
        #pragma unroll 8
        for (int m = ph * 192; m < ph * 192 + 192; ++m)
            acc += pb[m] * W[(long)m * NH];
        acc += __shfl_xor(acc, 1);
        acc += __shfl_xor(acc, 2);
        if (ph == 0) combB[idx] = acc + Wsb[idx];
    } else if (bid < 144) {
        int idx = (bid - 48) * 256 + t;
        q_f32[idx] = question[idx];
    } else if (bid < 240) {
        int idx = (bid - 144) * 256 + t;
        hT[idx] = 0.f;
    } else if (bid < 816) {
        int idx = (bid - 240) * 256 + t;    // 147,456 floats
        if (idx < 73728) sx[idx] = 0.f;
        else sh[idx - 73728] = 0.f;
    } else if (bid < 1072) {
        int idx = (bid - 816) * 256 + t;    // 65,536: scores = We_b (hop 0,
        scores[idx] = Web[idx >> 14];       // needed for fused leftover heads)
    } else if (bid < 3376) {
        if (tier < 2) return;
        __shared__ float tile[32][33];
        int bid2 = bid - 1072;
        int k = bid2 / 576, rem = bid2 % 576, tr = rem / 24, tc = rem % 24;
        const float* src = WsW + (long)k * HH;
        long dbase = (long)k * HH;
        int tx = t & 31, ty = t >> 5;
        #pragma unroll
        for (int i = 0; i < 4; ++i)
            tile[tx][ty + i*8] = src[(long)(tr*32 + ty + i*8) * NH + tc*32 + tx];
        __syncthreads();
        #pragma unroll
        for (int i = 0; i < 4; ++i) {
            float v = tile[ty + i*8][tx];
            u16 hv = f2bf(v);
            u16 lv = f2bf(v - bf2f(hv));
            long o = dbase + (long)(tc*32 + ty + i*8) * NH + tr*32 + tx;
            WsTH[o] = hv; WsTL[o] = lv;
        }
    } else if (bid < 5680) {
        if (tier < 2) return;
        long base = (long)(bid - 3376) * 1024 + t * 4;
        float4 v = *(const float4*)(pwW + base);
        ushort4 hv, lv;
        hv.x = f2bf(v.x); lv.x = f2bf(v.x - bf2f(hv.x));
        hv.y = f2bf(v.y); lv.y = f2bf(v.y - bf2f(hv.y));
        hv.z = f2bf(v.z); lv.z = f2bf(v.z - bf2f(hv.z));
        hv.w = f2bf(v.w); lv.w = f2bf(v.w - bf2f(hv.w));
        *(ushort4*)(pwH + base) = hv;
        *(ushort4*)(pwL + base) = lv;
    } else {
        if (!splitText) return;
        long base = (long)(bid - 5680) * 1024 + t * 4;
        float4 v = *(const float4*)(text + base);
        ushort4 hv;
        hv.x = f2bf(v.x);
        hv.y = f2bf(v.y);
        hv.z = f2bf(v.z);
        hv.w = f2bf(v.w);
        *(ushort4*)(textH + base) = hv;
    }
}

// combT[k][j][h] = sum_m WsT[k][j][m] * pw[k][h][m], split-bf16 3-MFMA.
__global__ __launch_bounds__(256) void comb_mfma_kernel(
    const u16* __restrict__ WsTH, const u16* __restrict__ WsTL,
    const u16* __restrict__ pwH, const u16* __restrict__ pwL,
    u16* __restrict__ combTH, u16* __restrict__ combTL)
{
    __shared__ __align__(16) u16 AsH[128 * 32];
    __shared__ __align__(16) u16 AsL[128 * 32];
    __shared__ __align__(16) u16 BsH[128 * 32];
    __shared__ __align__(16) u16 BsL[128 * 32];
    const int t = threadIdx.x;
    const int wave = t >> 6, lane = t & 63;
    const int k = blockIdx.z;
    const long m0 = (long)blockIdx.x * 128;   // j-rows
    const int n0 = blockIdx.y * 128;          // h-cols
    const u16* AH = WsTH + (long)k * HH;
    const u16* AL = WsTL + (long)k * HH;
    const u16* BH = pwH + (long)k * HH;
    const u16* BL = pwL + (long)k * HH;

    const int r = t >> 2, ch = t & 3;
    const int wm = (wave & 1) * 64, wn = (wave >> 1) * 64;
    const int fr = lane & 15, fq = lane >> 4;

    f32x4 acc[4][4];
    #pragma unroll
    for (int i = 0; i < 4; ++i)
        #pragma unroll
        for (int j = 0; j < 4; ++j) acc[i][j] = (f32x4){0.f, 0.f, 0.f, 0.f};

    for (int k0 = 0; k0 < NH; k0 += 32) {
        gld16(AH + (m0 + r)      * NH + k0 + ch*8, AsH + t*8);
        gld16(AH + (m0 + 64 + r) * NH + k0 + ch*8, AsH + 2048 + t*8);
        gld16(AL + (m0 + r)      * NH + k0 + ch*8, AsL + t*8);
        gld16(AL + (m0 + 64 + r) * NH + k0 + ch*8, AsL + 2048 + t*8);
        gld16(BH + (long)(n0 + r)      * NH + k0 + ch*8, BsH + t*8);
        gld16(BH + (long)(n0 + 64 + r) * NH + k0 + ch*8, BsH + 2048 + t*8);
        gld16(BL + (long)(n0 + r)      * NH + k0 + ch*8, BsL + t*8);
        gld16(BL + (long)(n0 + 64 + r) * NH + k0 + ch*8, BsL + 2048 + t*8);
        __syncthreads();
        bf16x8 afH[4], afL[4], bfH[4], bfL[4];
        #pragma unroll
        for (int i = 0; i < 4; ++i) {
            afH[i] = *(const bf16x8*)(AsH + (wm + i*16 + fr)*32 + fq*8);
            afL[i] = *(const bf16x8*)(AsL + (wm + i*16 + fr)*32 + fq*8);
            bfH[i] = *(const bf16x8*)(BsH + (wn + i*16 + fr)*32 + fq*8);
            bfL[i] = *(const bf16x8*)(BsL + (wn + i*16 + fr)*32 + fq*8);
        }
        #pragma unroll
        for (int i = 0; i < 4; ++i)
            #pragma unroll
            for (int j = 0; j < 4; ++j) {
                acc[i][j] = __builtin_amdgcn_mfma_f32_16x16x32_bf16(afH[i], bfH[j], acc[i][j], 0, 0, 0);
                acc[i][j] = __builtin_amdgcn_mfma_f32_16x16x32_bf16(afH[i], bfL[j], acc[i][j], 0, 0, 0);
                acc[i][j] = __builtin_amdgcn_mfma_f32_16x16x32_bf16(afL[i], bfH[j], acc[i][j], 0, 0, 0);
            }
        __syncthreads();
    }
    long kb = (long)k * HH;
    #pragma unroll
    for (int i = 0; i < 4; ++i) {
        long m = m0 + wm + i*16 + fq*4;       // j-row
        #pragma unroll
        for (int j = 0; j < 4; ++j) {
            long n = n0 + wn + j*16 + fr;     // h-col
            #pragma unroll
            for (int rr = 0; rr < 4; ++rr) {
                float v = acc[i][j][rr];
                u16 hv = f2bf(v);
                u16 lv = f2bf(v - bf2f(hv));
                combTH[kb + (m + rr) * NH + n] = hv;
                combTL[kb + (m + rr) * NH + n] = lv;
            }
        }
    }
}

// tier 0/1: comb[k][h][j] f32 VALU GEMM (proven R8 kernel).
__global__ __launch_bounds__(256) void comb_valu_kernel(
    const float* __restrict__ pwW, const float* __restrict__ WsW,
    float* __restrict__ comb)
{
    __shared__ float AtT[32][68];
    __shared__ float Bt[32][132];
    const int t = threadIdx.x;
    const int m0 = blockIdx.x * 64, j0 = blockIdx.y * 128, k = blockIdx.z;
    const float* A = pwW + (long)k * HH;
    const float* B = WsW + (long)k * HH;
    const int r4 = (t >> 4) * 4, c8 = (t & 15) * 8;
    float acc[4][8];
    #pragma unroll
    for (int rr = 0; rr < 4; ++rr)
        #pragma unroll
        for (int cc = 0; cc < 8; ++cc) acc[rr][cc] = 0.f;
    for (int h0 = 0; h0 < NH; h0 += 32) {
        #pragma unroll
        for (int p = 0; p < 8; ++p) {
            int idx = p * 256 + t;
            int r = idx >> 5, hh = idx & 31;
            AtT[hh][r] = A[(long)(m0 + r) * NH + h0 + hh];
        }
        #pragma unroll
        for (int p = 0; p < 16; ++p) {
            int idx = p * 256 + t;
            int hh = idx >> 7, c = idx & 127;
            Bt[hh][c] = B[(long)(h0 + hh) * NH + j0 + c];
        }
        __syncthreads();
        for (int hh = 0; hh < 32; ++hh) {
            float4 av  = *(const float4*)&AtT[hh][r4];
            float4 bv0 = *(const float4*)&Bt[hh][c8];
            float4 bv1 = *(const float4*)&Bt[hh][c8 + 4];
            float a[4] = {av.x, av.y, av.z, av.w};
            float bb[8] = {bv0.x, bv0.y, bv0.z, bv0.w, bv1.x, bv1.y, bv1.z, bv1.w};
            #pragma unroll
            for (int rr = 0; rr < 4; ++rr)
                #pragma unroll
                for (int cc = 0; cc < 8; ++cc) acc[rr][cc] += a[rr] * bb[cc];
        }
        __syncthreads();
    }
    float* C = comb + (long)k * HH;
    #pragma unroll
    for (int rr = 0; rr < 4; ++rr)
        #pragma unroll
        for (int cc = 0; cc < 8; ++cc)
            C[(long)(m0 + r4 + rr) * NH + j0 + c8 + cc] = acc[rr][cc];
}

// tier1: transpose+split comb f32 -> combTH/combTL. grid 2304.
__global__ void split_combT_kernel(const float* __restrict__ comb,
                                   u16* __restrict__ combTH, u16* __restrict__ combTL)
{
    __shared__ float tile[32][33];
    int bid = blockIdx.x, t = threadIdx.x;
    int k = bid / 576, rem = bid % 576, tr = rem / 24, tc = rem % 24;
    const float* src = comb + (long)k * HH;
    long dbase = (long)k * HH;
    int tx = t & 31, ty = t >> 5;
    #pragma unroll
    for (int i = 0; i < 4; ++i)
        tile[tx][ty + i*8] = src[(long)(tr*32 + ty + i*8) * NH + tc*32 + tx];
    __syncthreads();
    #pragma unroll
    for (int i = 0; i < 4; ++i) {
        float v = tile[ty + i*8][tx];
        u16 hv = f2bf(v);
        u16 lv = f2bf(v - bf2f(hv));
        long o = dbase + (long)(tc*32 + ty + i*8) * NH + tr*32 + tx;
        combTH[o] = hv; combTL[o] = lv;
    }
}

// TIER3: TP[k][bs][j] = bf16((text @ comb[k])[bs][j]) for heads [0, NSTORE).
// BK=64. AM=1: A hi via gld16 from textH. B split hi/lo (2 MFMA).
// grid (128, 6, NSTORE).
template <int AM>
__global__ __launch_bounds__(256) void tp_gemm_kernel(
    const float* __restrict__ textf, const u16* __restrict__ textH,
    const u16* __restrict__ combTH, const u16* __restrict__ combTL,
    u16* __restrict__ TP)
{
    __shared__ __align__(16) u16 AsH[128 * 64];
    __shared__ __align__(16) u16 BsH[128 * 64];
    __shared__ __align__(16) u16 BsL[128 * 64];
    const int t = threadIdx.x;
    const int wave = t >> 6, lane = t & 63;
    const int k = blockIdx.z;
    const long m0 = (long)blockIdx.x * 128;   // bs-rows
    const int n0 = blockIdx.y * 128;          // j-cols
    const u16* BH = combTH + (long)k * HH;
    const u16* BL = combTL + (long)k * HH;

    const int r = t >> 3, ch = t & 7;         // 32 rows x 8 chunks per gld16 call
    const int wm = (wave & 1) * 64, wn = (wave >> 1) * 64;
    const int fr = lane & 15, fq = lane >> 4;

    f32x4 acc[4][4];
    #pragma unroll
    for (int i = 0; i < 4; ++i)
        #pragma unroll
        for (int j = 0; j < 4; ++j) acc[i][j] = (f32x4){0.f, 0.f, 0.f, 0.f};

    for (int h0 = 0; h0 < NH; h0 += 64) {
        if (AM) {
            #pragma unroll
            for (int q = 0; q < 4; ++q)
                gld16(textH + (m0 + q*32 + r) * NH + h0 + ch*8, AsH + q*2048 + t*8);
        } else {
            #pragma unroll
            for (int p = 0; p < 8; ++p) {
                int task = p * 256 + t;
                int row = task >> 4, g = task & 15;
                float4 v = *(const float4*)(textf + (m0 + row) * NH + h0 + g*4);
                ushort4 hv;
                hv.x = f2bf(v.x);
                hv.y = f2bf(v.y);
                hv.z = f2bf(v.z);
                hv.w = f2bf(v.w);
                *(ushort4*)(AsH + row * 64 + g*4) = hv;
            }
        }
        #pragma unroll
        for (int q = 0; q < 4; ++q) {
            gld16(BH + (long)(n0 + q*32 + r) * NH + h0 + ch*8, BsH + q*2048 + t*8);
            gld16(BL + (long)(n0 + q*32 + r) * NH + h0 + ch*8, BsL + q*2048 + t*8);
        }
        __syncthreads();
        #pragma unroll
        for (int ks = 0; ks < 2; ++ks) {
            bf16x8 afH[4], bfH[4], bfL[4];
            #pragma unroll
            for (int i = 0; i < 4; ++i) {
                afH[i] = *(const bf16x8*)(AsH + (wm + i*16 + fr)*64 + ks*32 + fq*8);
                bfH[i] = *(const bf16x8*)(BsH + (wn + i*16 + fr)*64 + ks*32 + fq*8);
                bfL[i] = *(const bf16x8*)(BsL + (wn + i*16 + fr)*64 + ks*32 + fq*8);
            }
            #pragma unroll
            for (int i = 0; i < 4; ++i)
                #pragma unroll
                for (int j = 0; j < 4; ++j) {
                    acc[i][j] = __builtin_amdgcn_mfma_f32_16x16x32_bf16(afH[i], bfH[j], acc[i][j], 0, 0, 0);
                    acc[i][j] = __builtin_amdgcn_mfma_f32_16x16x32_bf16(afH[i], bfL[j], acc[i][j], 0, 0, 0);
                }
        }
        __syncthreads();
    }
    u16* out = TP + ((long)k * NBS + m0) * NH + n0;
    #pragma unroll
    for (int i = 0; i < 4; ++i) {
        #pragma unroll
        for (int rr = 0; rr < 4; ++rr) {
            int m = wm + i*16 + fq*4 + rr;
            #pragma unroll
            for (int j = 0; j < 4; ++j) {
                int n = wn + j*16 + fr;
                out[(long)m * NH + n] = f2bf(acc[i][j][rr]);
            }
        }
    }
}

// ---------------------------------------------------------------------------
// R10: cooperative hop-loop mega-kernel. grid 1024 x 256, 4 blocks/CU
// co-resident (__launch_bounds__(256,4), 32 KB LDS). Phases are verbatim
// ports of the proven R9 kernels; grid.sync() between phases.
// ---------------------------------------------------------------------------
__global__ __launch_bounds__(256, 4) void hop_loop_kernel(
    const u16* __restrict__ TP, float* __restrict__ W_ht,
    const float* __restrict__ combB,
    const float* __restrict__ WtW, const float* __restrict__ Wtb,
    const float* __restrict__ WeW, const float* __restrict__ Web,
    float* __restrict__ scores,
    const float* __restrict__ headw_W, const float* __restrict__ headw_b,
    const float* __restrict__ text,
    float* __restrict__ q_f32, float* __restrict__ hT, float* __restrict__ xT,
    float* __restrict__ sx, float* __restrict__ sh,
    const float* __restrict__ Wih, const float* __restrict__ Whh,
    const float* __restrict__ bih, const float* __restrict__ bhh,
    float* __restrict__ out_prob, float* __restrict__ out_h)
{
    cg::grid_group grid = cg::this_grid();
    __shared__ __align__(16) float smem[8192];   // 32 KB phase-union
    __shared__ float cred[4];
    __shared__ float cval[4];
    __shared__ int   cidx[4];
    const int bid = blockIdx.x, t = threadIdx.x;
    const int wave = t >> 6, lane = t & 63;

    for (int hop = 0; hop < 3; ++hop) {
        // ---- Phase 1: W_ht = Wtb + combB + q.Wt  (blocks 0..383) ----
        if (bid < 384) {
            int k = bid / 96, rem = bid % 96, b = rem / 3, jt = rem % 3;
            int j = jt * 256 + t;
            const float* W = WtW + (long)k * HH + j;
            const float* qb = q_f32 + b * NH;
            float acc = 0.f;
            #pragma unroll 8
            for (int h = 0; h < NH; ++h) acc += qb[h] * W[(long)h * NH];
            W_ht[(k*NB + b) * NH + j] = acc + Wtb[k * NH + j] + combB[k * NH + j];
        }
        grid.sync();
        // ---- Phase 2: score_pass (all 1024 blocks; 64 s-rows each) ----
        {
            int k = bid >> 8, rem = bid & 255;
            int b = rem >> 3, chunk = rem & 7;
            int s0 = chunk * 64;
            float* bias_s = smem;          // 768
            float* we_s   = smem + 768;    // 768
            for (int i = t; i < NH; i += 256) {
                bias_s[i] = W_ht[((k << 5) + b) * NH + i];
                we_s[i]   = WeW[k * NH + i];
            }
            __syncthreads();
            const u16* tpb = TP + ((long)k * NBS + (b << 9) + s0) * NH;
            const float web = Web[k];
            for (int sr = wave; sr < 64; sr += 4) {
                const u16* row = tpb + (long)sr * NH;
                float part = 0.f;
                #pragma unroll
                for (int p = 0; p < 3; ++p) {
                    const int j = p * 256 + lane * 4;
                    ushort4 v = *(const ushort4*)(row + j);
                    float4 bb = *(const float4*)(bias_s + j);
                    float4 ww = *(const float4*)(we_s + j);
                    part += tanh_fast(bf2f(v.x) + bb.x) * ww.x;
                    part += tanh_fast(bf2f(v.y) + bb.y) * ww.y;
                    part += tanh_fast(bf2f(v.z) + bb.z) * ww.z;
                    part += tanh_fast(bf2f(v.w) + bb.w) * ww.w;
                }
                part += __shfl_xor(part, 1);
                part += __shfl_xor(part, 2);
                part += __shfl_xor(part, 4);
                part += __shfl_xor(part, 8);
                part += __shfl_xor(part, 16);
                part += __shfl_xor(part, 32);
                if (lane == 0) scores[(((k << 5) + b) << 9) + s0 + sr] = part + web;
            }
        }
        grid.sync();
        // ---- Phase 3: softmax + argmax + xT build (blocks 0..31) ----
        if (bid < NB) {
            int b = bid;
            float (*sc)[NS] = (float(*)[NS])smem;    // 4*512 floats = 8 KB
            for (int i = t; i < NK * NS; i += 256) {
                int k = i >> 9, s = i & 511;
                sc[k][s] = scores[((k*NB + b) << 9) + s];
            }
            __syncthreads();
            float fac[NK];
            for (int k = 0; k < NK; ++k) {
                float v0 = sc[k][t], v1 = sc[k][t + 256];
                float m = fmaxf(v0, v1);
                #pragma unroll
                for (int o = 32; o > 0; o >>= 1) m = fmaxf(m, __shfl_xor(m, o));
                if (lane == 0) cred[wave] = m;
                __syncthreads();
                float mx = fmaxf(fmaxf(cred[0], cred[1]), fmaxf(cred[2], cred[3]));
                __syncthreads();
                float e0 = __expf(v0 - mx), e1 = __expf(v1 - mx);
                sc[k][t] = e0; sc[k][t + 256] = e1;
                float sm = e0 + e1;
                #pragma unroll
                for (int o = 32; o > 0; o >>= 1) sm += __shfl_xor(sm, o);
                if (lane == 0) cred[wave] = sm;
                __syncthreads();
                fac[k] = headw_W[k] / (cred[0] + cred[1] + cred[2] + cred[3]);
                __syncthreads();
            }
            float hwb = headw_b[0];
            float a0 = hwb, a1 = hwb;
            for (int k = 0; k < NK; ++k) { a0 += sc[k][t] * fac[k]; a1 += sc[k][t + 256] * fac[k]; }
            float ss = a0*a0 + a1*a1;
            #pragma unroll
            for (int o = 32; o > 0; o >>= 1) ss += __shfl_xor(ss, o);
            float bv; int bi;
            if (a0 >= a1) { bv = a0; bi = t; } else { bv = a1; bi = t + 256; }
            #pragma unroll
            for (int o = 1; o < 64; o <<= 1) {
                float ov = __shfl_xor(bv, o);
                int   oi = __shfl_xor(bi, o);
                if (ov > bv || (ov == bv && oi < bi)) { bv = ov; bi = oi; }
            }
            if (lane == 0) { cred[wave] = ss; cval[wave] = bv; cidx[wave] = bi; }
            __syncthreads();
            float scale = sqrtf(cred[0] + cred[1] + cred[2] + cred[3]);
            float mbv = cval[0]; int mbi = cidx[0];
            #pragma unroll
            for (int w = 1; w < 4; ++w)
                if (cval[w] > mbv || (cval[w] == mbv && cidx[w] < mbi)) { mbv = cval[w]; mbi = cidx[w]; }
            int idx = mbi;
            if (hop == 0) {
                out_prob[(b << 9) + t]       = a0 / scale;
                out_prob[(b << 9) + t + 256] = a1 / scale;
            }
            const float* trow = text + (long)(b * NS + idx) * NH;
            for (int i = t; i < NH; i += 256) {
                xT[i * NB + b]        = q_f32[b*NH + i];
                xT[(NH + i) * NB + b] = trow[i];
            }
        }
        grid.sync();
        // ---- Phase 4: GRU matvec partials (blocks 0..323) ----
        if (bid < 324) {
            float* xs = smem;                        // 8192 floats
            int jx = bid % 36, cgi = bid / 36;
            int tj = t & 63, tq = t >> 6;
            int j = jx * 64 + tj;
            const float* W; const float* src; float* dst; int c;
            if (cgi < 6) { W = Wih; src = xT; dst = sx; c = cgi; }
            else         { W = Whh; src = hT; dst = sh; c = cgi - 6; }
            for (int idx = t; idx < 8192; idx += 256) xs[idx] = src[c * 8192 + idx];
            __syncthreads();
            float acc[8];
            #pragma unroll
            for (int bq = 0; bq < 8; ++bq) acc[bq] = 0.f;
            #pragma unroll 8
            for (int ii = 0; ii < 256; ++ii) {
                float w = W[(long)(c * 256 + ii) * H3 + j];
                #pragma unroll
                for (int bq = 0; bq < 8; ++bq) acc[bq] += xs[ii * 32 + tq * 8 + bq] * w;
            }
            #pragma unroll
            for (int bq = 0; bq < 8; ++bq)
                atomicAdd(&dst[(long)(tq * 8 + bq) * H3 + j], acc[bq]);
        }
        grid.sync();
        // ---- Phase 5: gate + h/q update; re-zero sx/sh (blocks 0..95) ----
        if (bid < 96) {
            int gid = bid * 256 + t;
            int b = gid / NH, j = gid % NH;
            float xr = bih[j]        + sx[b*H3 + j];
            float xz = bih[NH + j]   + sx[b*H3 + NH + j];
            float xn = bih[1536 + j] + sx[b*H3 + 1536 + j];
            float hr = bhh[j]        + sh[b*H3 + j];
            float hz = bhh[NH + j]   + sh[b*H3 + NH + j];
            float hn = bhh[1536 + j] + sh[b*H3 + 1536 + j];
            sx[b*H3 + j] = 0.f; sx[b*H3 + NH + j] = 0.f; sx[b*H3 + 1536 + j] = 0.f;
            sh[b*H3 + j] = 0.f; sh[b*H3 + NH + j] = 0.f; sh[b*H3 + 1536 + j] = 0.f;
            float r = sig_fast(xr + hr);
            float z = sig_fast(xz + hz);
            float n = tanh_fast(xn + r * hn);
            float hp = hT[j * NB + b];
            float hnew = (1.f - z) * n + z * hp;
            hT[j * NB + b] = hnew;
            q_f32[gid] = hnew;
            out_h[(long)(b * 3 + hop) * NH + j] = hnew;
        }
        grid.sync();
    }
}

// ---------------------------------------------------------------------------
// Fallback per-hop kernels (R9-proven; used when cooperative launch fails
// or nstore < NK).
// ---------------------------------------------------------------------------
__global__ __launch_bounds__(256) void score_pass_kernel(
    const u16* __restrict__ TP, const float* __restrict__ W_ht,
    const float* __restrict__ WeW, const float* __restrict__ Web,
    float* __restrict__ scores)
{
    __shared__ __align__(16) float bias_s[NH];
    __shared__ __align__(16) float we_s[NH];
    const int t = threadIdx.x;
    const int k = blockIdx.z, b = blockIdx.y;
    const int s0 = blockIdx.x * 32;
    for (int i = t; i < NH; i += 256) {
        bias_s[i] = W_ht[((k << 5) + b) * NH + i];
        we_s[i]   = WeW[k * NH + i];
    }
    __syncthreads();
    const int wave = t >> 6, lane = t & 63;
    const u16* tpb = TP + ((long)k * NBS + (b << 9) + s0) * NH;
    const float web = Web[k];
    for (int sr = wave; sr < 32; sr += 4) {
        const u16* row = tpb + (long)sr * NH;
        float part = 0.f;
        #pragma unroll
        for (int p = 0; p < 3; ++p) {
            const int j = p * 256 + lane * 4;
            ushort4 v = *(const ushort4*)(row + j);
            float4 bb = *(const float4*)(bias_s + j);
            float4 ww = *(const float4*)(we_s + j);
            part += tanh_fast(bf2f(v.x) + bb.x) * ww.x;
            part += tanh_fast(bf2f(v.y) + bb.y) * ww.y;
            part += tanh_fast(bf2f(v.z) + bb.z) * ww.z;
            part += tanh_fast(bf2f(v.w) + bb.w) * ww.w;
        }
        part += __shfl_xor(part, 1);
        part += __shfl_xor(part, 2);
        part += __shfl_xor(part, 4);
        part += __shfl_xor(part, 8);
        part += __shfl_xor(part, 16);
        part += __shfl_xor(part, 32);
        if (lane == 0) scores[(((k << 5) + b) << 9) + s0 + sr] = part + web;
    }
}

__global__ void init_scores_kernel(const float* __restrict__ Web,
                                   float* __restrict__ scores, int koff)
{
    int idx = (koff << 14) + blockIdx.x * 256 + threadIdx.x;
    scores[idx] = Web[idx >> 14];
}

__global__ __launch_bounds__(256) void wht2_kernel(
    const float* __restrict__ q, const float* __restrict__ WtW,
    const float* __restrict__ combB, const float* __restrict__ Wtb,
    float* __restrict__ W_ht)
{
    int bid = blockIdx.x;                 // 4k x 32b x 3jt
    int k = bid / 96, rem = bid % 96, b = rem / 3, jt = rem % 3;
    int j = jt * 256 + threadIdx.x;
    const float* W = WtW + (long)k * HH + j;
    const float* qb = q + b * NH;
    float acc = 0.f;
    #pragma unroll 8
    for (int h = 0; h < NH; ++h) acc += qb[h] * W[(long)h * NH];
    W_ht[(k*NB + b) * NH + j] = acc + Wtb[k * NH + j] + combB[k * NH + j];
}

template <int AM>
__global__ __launch_bounds__(256) void fused_scores_mfma(
    const float* __restrict__ textf,
    const u16* __restrict__ textH, const u16* __restrict__ textL,
    const u16* __restrict__ combTH, const u16* __restrict__ combTL,
    const float* __restrict__ W_ht,
    const float* __restrict__ WeW, float* __restrict__ scores, int koff)
{
    __shared__ __align__(16) u16 AsH[128 * 32];
    __shared__ __align__(16) u16 AsL[128 * 32];
    __shared__ __align__(16) u16 BsH[128 * 32];
    __shared__ __align__(16) u16 BsL[128 * 32];
    __shared__ float wht_s[128];
    __shared__ float we_s[128];
    __shared__ float sred[128];
    const int t = threadIdx.x;
    const int wave = t >> 6, lane = t & 63;
    const int k = koff + blockIdx.z;
    const long m0 = (long)blockIdx.x * 128;
    const int n0 = blockIdx.y * 128;
    const int b = (int)(m0 >> 9), srow = (int)(m0 & 511);
    const u16* BH = combTH + (long)k * HH;
    const u16* BL = combTL + (long)k * HH;

    if (t < 128) {
        wht_s[t] = W_ht[((k << 5) + b) * NH + n0 + t];
        we_s[t]  = WeW[k * NH + n0 + t];
        sred[t]  = 0.f;
    }

    const int r = t >> 2, ch = t & 3;
    const int wm = (wave & 1) * 64, wn = (wave >> 1) * 64;
    const int fr = lane & 15, fq = lane >> 4;

    f32x4 acc[4][4];
    #pragma unroll
    for (int i = 0; i < 4; ++i)
        #pragma unroll
        for (int j = 0; j < 4; ++j) acc[i][j] = (f32x4){0.f, 0.f, 0.f, 0.f};

    for (int h0 = 0; h0 < NH; h0 += 32) {
        if (AM) {
            gld16(textH + (m0 + r)      * NH + h0 + ch*8, AsH + t*8);
            gld16(textH + (m0 + 64 + r) * NH + h0 + ch*8, AsH + 2048 + t*8);
            gld16(textL + (m0 + r)      * NH + h0 + ch*8, AsL + t*8);
            gld16(textL + (m0 + 64 + r) * NH + h0 + ch*8, AsL + 2048 + t*8);
        } else {
            #pragma unroll
            for (int p = 0; p < 4; ++p) {
                int task = p * 256 + t;
                int row = task >> 3, g = task & 7;
                float4 v = *(const float4*)(textf + (m0 + row) * NH + h0 + g*4);
                ushort4 hv, lv;
                hv.x = f2bf(v.x); lv.x = f2bf(v.x - bf2f(hv.x));
                hv.y = f2bf(v.y); lv.y = f2bf(v.y - bf2f(hv.y));
                hv.z = f2bf(v.z); lv.z = f2bf(v.z - bf2f(hv.z));
                hv.w = f2bf(v.w); lv.w = f2bf(v.w - bf2f(hv.w));
                *(ushort4*)(AsH + row * 32 + g*4) = hv;
                *(ushort4*)(AsL + row * 32 + g*4) = lv;
            }
        }
        gld16(BH + (long)(n0 + r)      * NH + h0 + ch*8, BsH + t*8);
        gld16(BH + (long)(n0 + 64 + r) * NH + h0 + ch*8, BsH + 2048 + t*8);
        gld16(BL + (long)(n0 + r)      * NH + h0 + ch*8, BsL + t*8);
        gld16(BL + (long)(n0 + 64 + r) * NH + h0 + ch*8, BsL + 2048 + t*8);
        __syncthreads();
        bf16x8 afH[4], afL[4], bfH[4], bfL[4];
        #pragma unroll
        for (int i = 0; i < 4; ++i) {
            afH[i] = *(const bf16x8*)(AsH + (wm + i*16 + fr)*32 + fq*8);
            afL[i] = *(const bf16x8*)(AsL + (wm + i*16 + fr)*32 + fq*8);
            bfH[i] = *(const bf16x8*)(BsH + (wn + i*16 + fr)*32 + fq*8);
            bfL[i] = *(const bf16x8*)(BsL + (wn + i*16 + fr)*32 + fq*8);
        }
        #pragma unroll
        for (int i = 0; i < 4; ++i)
            #pragma unroll
            for (int j = 0; j < 4; ++j) {
                acc[i][j] = __builtin_amdgcn_mfma_f32_16x16x32_bf16(afH[i], bfH[j], acc[i][j], 0, 0, 0);
                acc[i][j] = __builtin_amdgcn_mfma_f32_16x16x32_bf16(afH[i], bfL[j], acc[i][j], 0, 0, 0);
                acc[i][j] = __builtin_amdgcn_mfma_f32_16x16x32_bf16(afL[i], bfH[j], acc[i][j], 0, 0, 0);
            }
        __syncthreads();
    }
    #pragma unroll
    for (int i = 0; i < 4; ++i) {
        #pragma unroll
        for (int rr = 0; rr < 4; ++rr) {
            int m = wm + i*16 + fq*4 + rr;
            float part = 0.f;
            #pragma unroll
            for (int j = 0; j < 4; ++j) {
                int n = wn + j*16 + fr;
                part += tanh_fast(acc[i][j][rr] + wht_s[n]) * we_s[n];
            }
            part += __shfl_xor(part, 1);
            part += __shfl_xor(part, 2);
            part += __shfl_xor(part, 4);
            part += __shfl_xor(part, 8);
            if (fr == 0) atomicAdd(&sred[m], part);
        }
    }
    __syncthreads();
    if (t < 128)
        atomicAdd(&scores[(((k << 5) + b) << 9) + srow + t], sred[t]);
}

__global__ __launch_bounds__(256) void fused_scores_valu(
    const float* __restrict__ text, const float* __restrict__ comb,
    const float* __restrict__ W_ht,
    const float* __restrict__ WeW, float* __restrict__ scores)
{
    __shared__ float AtT[32][68];
    __shared__ float Bt[32][132];
    __shared__ float wht_s[128];
    __shared__ float we_s[128];
    __shared__ float sred[64];
    const int t = threadIdx.x;
    const int row0 = blockIdx.x * 64;
    const int j0 = blockIdx.y * 128, k = blockIdx.z;
    const int b = row0 >> 9, s0 = row0 & 511;
    const float* B = comb + (long)k * HH;
    const int r4 = (t >> 4) * 4, c8 = (t & 15) * 8;
    if (t < 128) {
        wht_s[t] = W_ht[((k << 5) + b) * NH + j0 + t];
        we_s[t]  = WeW[k * NH + j0 + t];
    }
    if (t < 64) sred[t] = 0.f;
    float acc[4][8];
    #pragma unroll
    for (int rr = 0; rr < 4; ++rr)
        #pragma unroll
        for (int cc = 0; cc < 8; ++cc) acc[rr][cc] = 0.f;
    for (int h0 = 0; h0 < NH; h0 += 32) {
        #pragma unroll
        for (int p = 0; p < 8; ++p) {
            int idx = p * 256 + t;
            int r = idx >> 5, hh = idx & 31;
            AtT[hh][r] = text[(long)(row0 + r) * NH + h0 + hh];
        }
        #pragma unroll
        for (int p = 0; p < 16; ++p) {
            int idx = p * 256 + t;
            int hh = idx >> 7, c = idx & 127;
            Bt[hh][c] = B[(long)(h0 + hh) * NH + j0 + c];
        }
        __syncthreads();
        for (int hh = 0; hh < 32; ++hh) {
            float4 av  = *(const float4*)&AtT[hh][r4];
            float4 bv0 = *(const float4*)&Bt[hh][c8];
            float4 bv1 = *(const float4*)&Bt[hh][c8 + 4];
            float a[4] = {av.x, av.y, av.z, av.w};
            float bb[8] = {bv0.x, bv0.y, bv0.z, bv0.w, bv1.x, bv1.y, bv1.z, bv1.w};
            #pragma unroll
            for (int rr = 0; rr < 4; ++rr)
                #pragma unroll
                for (int cc = 0; cc < 8; ++cc) acc[rr][cc] += a[rr] * bb[cc];
        }
        __syncthreads();
    }
    float part[4] = {0.f, 0.f, 0.f, 0.f};
    #pragma unroll
    for (int rr = 0; rr < 4; ++rr)
        #pragma unroll
        for (int cc = 0; cc < 8; ++cc)
            part[rr] += tanh_fast(acc[rr][cc] + wht_s[c8 + cc]) * we_s[c8 + cc];
    #pragma unroll
    for (int rr = 0; rr < 4; ++rr)
        atomicAdd(&sred[r4 + rr], part[rr]);
    __syncthreads();
    if (t < 64)
        atomicAdd(&scores[(((k << 5) + b) << 9) + s0 + t], sred[t]);
}

__global__ void softmax_kernel(const float* __restrict__ scores,
                               const float* __restrict__ headw_W, const float* __restrict__ headw_b,
                               const float* __restrict__ text,
                               const float* __restrict__ q_f32,
                               float* __restrict__ xT, float* __restrict__ out_prob, int hop)
{
    __shared__ float sc[NK][NS];
    __shared__ float cred[4];
    __shared__ float cval[4];
    __shared__ int   cidx[4];
    int b = blockIdx.x, t = threadIdx.x;
    int wave = t >> 6, lane = t & 63;
    for (int i = t; i < NK * NS; i += 256) {
        int k = i >> 9, s = i & 511;
        sc[k][s] = scores[((k*NB + b) << 9) + s];
    }
    __syncthreads();
    float fac[NK];
    for (int k = 0; k < NK; ++k) {
        float v0 = sc[k][t], v1 = sc[k][t + 256];
        float m = fmaxf(v0, v1);
        #pragma unroll
        for (int o = 32; o > 0; o >>= 1) m = fmaxf(m, __shfl_xor(m, o));
        if (lane == 0) cred[wave] = m;
        __syncthreads();
        float mx = fmaxf(fmaxf(cred[0], cred[1]), fmaxf(cred[2], cred[3]));
        __syncthreads();
        float e0 = __expf(v0 - mx), e1 = __expf(v1 - mx);
        sc[k][t] = e0; sc[k][t + 256] = e1;
        float sm = e0 + e1;
        #pragma unroll
        for (int o = 32; o > 0; o >>= 1) sm += __shfl_xor(sm, o);
        if (lane == 0) cred[wave] = sm;
        __syncthreads();
        fac[k] = headw_W[k] / (cred[0] + cred[1] + cred[2] + cred[3]);
        __syncthreads();
    }
    float hwb = headw_b[0];
    float a0 = hwb, a1 = hwb;
    for (int k = 0; k < NK; ++k) { a0 += sc[k][t] * fac[k]; a1 += sc[k][t + 256] * fac[k]; }
    float ss = a0*a0 + a1*a1;
    #pragma unroll
    for (int o = 32; o > 0; o >>= 1) ss += __shfl_xor(ss, o);
    float bv; int bi;
    if (a0 >= a1) { bv = a0; bi = t; } else { bv = a1; bi = t + 256; }
    #pragma unroll
    for (int o = 1; o < 64; o <<= 1) {
        float ov = __shfl_xor(bv, o);
        int   oi = __shfl_xor(bi, o);
        if (ov > bv || (ov == bv && oi < bi)) { bv = ov; bi = oi; }
    }
    if (lane == 0) { cred[wave] = ss; cval[wave] = bv; cidx[wave] = bi; }
    __syncthreads();
    float scale = sqrtf(cred[0] + cred[1] + cred[2] + cred[3]);
    float mbv = cval[0]; int mbi = cidx[0];
    #pragma unroll
    for (int w = 1; w < 4; ++w)
        if (cval[w] > mbv || (cval[w] == mbv && cidx[w] < mbi)) { mbv = cval[w]; mbi = cidx[w]; }
    int idx = mbi;
    if (hop == 0) {
        out_prob[(b << 9) + t]       = a0 / scale;
        out_prob[(b << 9) + t + 256] = a1 / scale;
    }
    const float* trow = text + (long)(b * NS + idx) * NH;
    for (int i = t; i < NH; i += 256) {
        xT[i * NB + b]        = q_f32[b*NH + i];
        xT[(NH + i) * NB + b] = trow[i];
    }
}

__global__ __launch_bounds__(256) void gru_mm3_kernel(
    const float* __restrict__ Wih, const float* __restrict__ Whh,
    const float* __restrict__ xT, const float* __restrict__ hT,
    float* __restrict__ sx, float* __restrict__ sh)
{
    __shared__ float xs[8192];
    int t = threadIdx.x;
    int tj = t & 63, tq = t >> 6;
    int j = blockIdx.x * 64 + tj;
    int cgi = blockIdx.y;
    const float* W; const float* src; float* dst; int c;
    if (cgi < 6) { W = Wih; src = xT; dst = sx; c = cgi; }
    else         { W = Whh; src = hT; dst = sh; c = cgi - 6; }
    for (int idx = t; idx < 8192; idx += 256) xs[idx] = src[c * 8192 + idx];
    __syncthreads();
    float acc[8];
    #pragma unroll
    for (int bq = 0; bq < 8; ++bq) acc[bq] = 0.f;
    #pragma unroll 8
    for (int ii = 0; ii < 256; ++ii) {
        float w = W[(long)(c * 256 + ii) * H3 + j];
        #pragma unroll
        for (int bq = 0; bq < 8; ++bq) acc[bq] += xs[ii * 32 + tq * 8 + bq] * w;
    }
    #pragma unroll
    for (int bq = 0; bq < 8; ++bq)
        atomicAdd(&dst[(long)(tq * 8 + bq) * H3 + j], acc[bq]);
}

__global__ void gate_kernel(const float* __restrict__ bih, const float* __restrict__ bhh,
                            float* __restrict__ sx, float* __restrict__ sh,
                            float* __restrict__ hT, float* __restrict__ q_f32,
                            float* __restrict__ out_h, int hop)
{
    int gid = blockIdx.x * 256 + threadIdx.x;
    int b = gid / NH, j = gid % NH;
    float xr = bih[j]        + sx[b*H3 + j];
    float xz = bih[NH + j]   + sx[b*H3 + NH + j];
    float xn = bih[1536 + j] + sx[b*H3 + 1536 + j];
    float hr = bhh[j]        + sh[b*H3 + j];
    float hz = bhh[NH + j]   + sh[b*H3 + NH + j];
    float hn = bhh[1536 + j] + sh[b*H3 + 1536 + j];
    sx[b*H3 + j] = 0.f; sx[b*H3 + NH + j] = 0.f; sx[b*H3 + 1536 + j] = 0.f;
    sh[b*H3 + j] = 0.f; sh[b*H3 + NH + j] = 0.f; sh[b*H3 + 1536 + j] = 0.f;
    float r = sig_fast(xr + hr);
    float z = sig_fast(xz + hz);
    float n = tanh_fast(xn + r * hn);
    float hp = hT[j * NB + b];
    float hnew = (1.f - z) * n + z * hp;
    hT[j * NB + b] = hnew;
    q_f32[gid] = hnew;
    out_h[(long)(b * 3 + hop) * NH + j] = hnew;
}

// ---------------------------------------------------------------------------
extern "C" void kernel_launch(void* const* d_in, const int* in_sizes, int n_in,
                              void* d_out, int out_size, void* d_ws, size_t ws_size,
                              hipStream_t stream)
{
    const float* question = (const float*)d_in[0];
    const float* text     = (const float*)d_in[1];
    const float* pw_W     = (const float*)d_in[2];
    const float* pw_b     = (const float*)d_in[3];
    const float* Ws_W     = (const float*)d_in[4];
    const float* Ws_b     = (const float*)d_in[5];
    const float* Wt_W     = (const float*)d_in[6];
    const float* Wt_b     = (const float*)d_in[7];
    const float* We_W     = (const float*)d_in[8];
    const float* We_b     = (const float*)d_in[9];
    const float* headw_W  = (const float*)d_in[10];
    const float* headw_b  = (const float*)d_in[11];
    const float* Wih      = (const float*)d_in[12];
    const float* Whh      = (const float*)d_in[13];
    const float* bih      = (const float*)d_in[14];
    const float* bhh      = (const float*)d_in[15];

    char* ws = (char*)d_ws;
    float* comb   = (float*)(ws + 0);
    float* combB  = (float*)(ws + 9437184);
    float* W_ht   = (float*)(ws + 9449472);
    float* scores = (float*)(ws + 9842688);
    float* q_f32  = (float*)(ws + 10104832);
    float* hT     = (float*)(ws + 10203136);
    float* xT     = (float*)(ws + 10301440);
    float* sx     = (float*)(ws + 10498048);
    float* sh     = (float*)(ws + 10792960);
    u16*   combTH = (u16*)  (ws + 11087872);
    u16*   combTL = (u16*)  (ws + 15806464);
    u16*   TP     = (u16*)  (ws + 20525056);
    u16*   textH  = (u16*)  (ws + 121188352);
    // prep scratch overlaid on TP region (dead before tp_gemm runs):
    u16*   WsTH   = (u16*)  (ws + 20525056);
    u16*   WsTL   = (u16*)  (ws + 25243648);
    u16*   pwH    = (u16*)  (ws + 29962240);
    u16*   pwL    = (u16*)  (ws + 34680832);

    int nstore = 0;
    if (ws_size >= (size_t)70856704) {
        long avail = (long)ws_size - 20525056L;
        nstore = (int)(avail / 25165824L);
        if (nstore > NK) nstore = NK;
    }
    const int tier = (nstore >= 1) ? 3
                   : (ws_size >= (size_t)20525056) ? 1 : 0;
    const bool haveTextH = (tier == 3) && (nstore == NK)
                        && (ws_size >= (size_t)146354176);

    float* out_prob = (float*)d_out;
    float* out_h    = (float*)d_out + NB * NS;

    const int prepGrid = haveTextH ? 17968 : (tier >= 2 ? 5680 : 1072);
    prep_kernel<<<prepGrid, 256, 0, stream>>>(
        Ws_W, pw_b, Ws_b, combB, question, q_f32, hT, sx, sh, We_b, scores,
        pw_W, WsTH, WsTL, pwH, pwL, text, textH,
        tier >= 3 ? 2 : tier, haveTextH ? 1 : 0);

    if (tier == 3) {
        comb_mfma_kernel<<<dim3(6, 6, 4), 256, 0, stream>>>(WsTH, WsTL, pwH, pwL,
                                                            combTH, combTL);
        // scratch dead from here; TP overwrites it.
        if (haveTextH) {
            tp_gemm_kernel<1><<<dim3(128, 6, nstore), 256, 0, stream>>>(
                text, textH, combTH, combTL, TP);
        } else {
            tp_gemm_kernel<0><<<dim3(128, 6, nstore), 256, 0, stream>>>(
                text, nullptr, combTH, combTL, TP);
        }
    } else {
        comb_valu_kernel<<<dim3(12, 6, 4), 256, 0, stream>>>(pw_W, Ws_W, comb);
        if (tier == 1)
            split_combT_kernel<<<2304, 256, 0, stream>>>(comb, combTH, combTL);
    }

    // --- R10: single cooperative launch for the full 3-hop loop (all heads
    // stored). Falls back to the R9 sequence if the launch is rejected. ---
    bool coopDone = false;
    if (tier == 3 && nstore == NK) {
        void* args[] = {
            (void*)&TP, (void*)&W_ht, (void*)&combB, (void*)&Wt_W, (void*)&Wt_b,
            (void*)&We_W, (void*)&We_b, (void*)&scores,
            (void*)&headw_W, (void*)&headw_b, (void*)&text,
            (void*)&q_f32, (void*)&hT, (void*)&xT, (void*)&sx, (void*)&sh,
            (void*)&Wih, (void*)&Whh, (void*)&bih, (void*)&bhh,
            (void*)&out_prob, (void*)&out_h
        };
        hipError_t cerr = hipLaunchCooperativeKernel(
            reinterpret_cast<void*>(hop_loop_kernel),
            dim3(1024), dim3(256), args, 0, stream);
        if (cerr == hipSuccess) coopDone = true;
        else (void)hipGetLastError();   // clear; use fallback below
    }

    if (!coopDone) {
        for (int hop = 0; hop < 3; ++hop) {
            wht2_kernel<<<384, 256, 0, stream>>>(q_f32, Wt_W, combB, Wt_b, W_ht);
            if (tier == 3) {
                score_pass_kernel<<<dim3(16, 32, nstore), 256, 0, stream>>>(
                    TP, W_ht, We_W, We_b, scores);
                if (nstore < NK) {
                    if (hop > 0)
                        init_scores_kernel<<<(NK - nstore) * 64, 256, 0, stream>>>(
                            We_b, scores, nstore);
                    fused_scores_mfma<0><<<dim3(128, 6, NK - nstore), 256, 0, stream>>>(
                        text, nullptr, nullptr, combTH, combTL, W_ht, We_W,
                        scores, nstore);
                }
            } else if (tier == 1) {
                init_scores_kernel<<<256, 256, 0, stream>>>(We_b, scores, 0);
                fused_scores_mfma<0><<<dim3(128, 6, 4), 256, 0, stream>>>(
                    text, nullptr, nullptr, combTH, combTL, W_ht, We_W, scores, 0);
            } else {
                init_scores_kernel<<<256, 256, 0, stream>>>(We_b, scores, 0);
                fused_scores_valu<<<dim3(256, 6, 4), 256, 0, stream>>>(
                    text, comb, W_ht, We_W, scores);
            }
            softmax_kernel<<<32, 256, 0, stream>>>(scores, headw_W, headw_b, text,
                                                   q_f32, xT, out_prob, hop);
            gru_mm3_kernel<<<dim3(36, 9), 256, 0, stream>>>(Wih, Whh, xT, hT, sx, sh);
            gate_kernel<<<96, 256, 0, stream>>>(bih, bhh, sx, sh, hT, q_f32, out_h, hop);
        }
    }
}

// Round 12
// 634.350 us; speedup vs baseline: 3.8540x; 3.8540x over previous
//
#include <hip/hip_runtime.h>

typedef unsigned short u16;
typedef __bf16 bf16x8 __attribute__((ext_vector_type(8)));
typedef float f32x4 __attribute__((ext_vector_type(4)));

#define NB 32          // batch
#define NS 512         // seq
#define NH 768         // hidden
#define NK 4           // heads
#define NBS 16384      // B*S
#define H3 2304        // 3H
#define HH 589824      // 768*768

__device__ inline float bf2f(u16 u) {
    unsigned x = ((unsigned)u) << 16;
    return __builtin_bit_cast(float, x);
}
__device__ inline u16 f2bf(float f) {
    unsigned u = __builtin_bit_cast(unsigned, f);
    u += 0x7fffu + ((u >> 16) & 1u);
    return (u16)(u >> 16);
}
// fast tanh: 1 - 2*rcp(exp(2x)+1). ~5 VALU vs ~20+ for libm tanhf. err ~1e-6.
__device__ inline float tanh_fast(float x) {
    float e = __expf(2.f * x);
    return 1.f - 2.f * __builtin_amdgcn_rcpf(e + 1.f);
}
__device__ inline float sig_fast(float x) {
    return __builtin_amdgcn_rcpf(1.f + __expf(-x));
}
// async global->LDS, 16B/lane; LDS dst = wave-uniform base + lane*16 (m97 recipe).
__device__ inline void gld16(const u16* g, u16* l) {
    __builtin_amdgcn_global_load_lds(
        (const __attribute__((address_space(1))) unsigned int*)g,
        (__attribute__((address_space(3))) unsigned int*)l, 16, 0, 0);
}

// ---------------------------------------------------------------------------
// Workspace layout (bytes): unchanged from R9.
//  comb @ 0 | combB @ 9,437,184 | W_ht @ 9,449,472 | scores @ 9,842,688
//  q_f32 @ 10,104,832 | hT @ 10,203,136 | xT @ 10,301,440
//  sx @ 10,498,048 | sh @ 10,792,960 | combTH @ 11,087,872 | combTL @ 15,806,464
//  TP @ 20,525,056 (NSTORE x 25,165,824 bf16) | textH @ 121,188,352
//  prep scratch overlaid on TP: WsTH/WsTL/pwH/pwL.
//
// R12: REVERT to R9 (631 us proven) after R11's cooperative experiment
// measured grid.sync at ~120 us/sync on MI355X (18 syncs -> 2158 us kernel;
// VALUBusy 3.6%) — CG grid barriers are unusable in hot loops on this chip.
// Only delta vs R9: score_pass widened to 64 rows/block, grid (8,32,4)
// (this exact 64-row logic ran correctly inside R11's passing coop kernel).
// ---------------------------------------------------------------------------

// P: one-time prep. grid up to 17968 (sections gated).
__global__ void prep_kernel(const float* __restrict__ WsW, const float* __restrict__ pwb,
                            const float* __restrict__ Wsb, float* __restrict__ combB,
                            const float* __restrict__ question,
                            float* __restrict__ q_f32, float* __restrict__ hT,
                            float* __restrict__ sx, float* __restrict__ sh,
                            const float* __restrict__ Web, float* __restrict__ scores,
                            const float* __restrict__ pwW,
                            u16* __restrict__ WsTH, u16* __restrict__ WsTL,
                            u16* __restrict__ pwH, u16* __restrict__ pwL,
                            const float* __restrict__ text, u16* __restrict__ textH,
                            int tier, int splitText)
{
    int bid = blockIdx.x, t = threadIdx.x;
    if (bid < 48) {
        int idx = bid * 64 + (t >> 2);      // 0..3071
        int ph = t & 3;
        int k = idx / NH, j = idx % NH;
        const float* W = WsW + (long)k * HH + j;
        const float* pb = pwb + k * NH;
        float acc = 0.f;
        #pragma unroll 8
        for (int m = ph * 192; m < ph * 192 + 192; ++m)
            acc += pb[m] * W[(long)m * NH];
        acc += __shfl_xor(acc, 1);
        acc += __shfl_xor(acc, 2);
        if (ph == 0) combB[idx] = acc + Wsb[idx];
    } else if (bid < 144) {
        int idx = (bid - 48) * 256 + t;
        q_f32[idx] = question[idx];
    } else if (bid < 240) {
        int idx = (bid - 144) * 256 + t;
        hT[idx] = 0.f;
    } else if (bid < 816) {
        int idx = (bid - 240) * 256 + t;    // 147,456 floats
        if (idx < 73728) sx[idx] = 0.f;
        else sh[idx - 73728] = 0.f;
    } else if (bid < 1072) {
        int idx = (bid - 816) * 256 + t;    // 65,536: scores = We_b (hop 0,
        scores[idx] = Web[idx >> 14];       // needed for fused leftover heads)
    } else if (bid < 3376) {
        if (tier < 2) return;
        __shared__ float tile[32][33];
        int bid2 = bid - 1072;
        int k = bid2 / 576, rem = bid2 % 576, tr = rem / 24, tc = rem % 24;
        const float* src = WsW + (long)k * HH;
        long dbase = (long)k * HH;
        int tx = t & 31, ty = t >> 5;
        #pragma unroll
        for (int i = 0; i < 4; ++i)
            tile[tx][ty + i*8] = src[(long)(tr*32 + ty + i*8) * NH + tc*32 + tx];
        __syncthreads();
        #pragma unroll
        for (int i = 0; i < 4; ++i) {
            float v = tile[ty + i*8][tx];
            u16 hv = f2bf(v);
            u16 lv = f2bf(v - bf2f(hv));
            long o = dbase + (long)(tc*32 + ty + i*8) * NH + tr*32 + tx;
            WsTH[o] = hv; WsTL[o] = lv;
        }
    } else if (bid < 5680) {
        if (tier < 2) return;
        long base = (long)(bid - 3376) * 1024 + t * 4;
        float4 v = *(const float4*)(pwW + base);
        ushort4 hv, lv;
        hv.x = f2bf(v.x); lv.x = f2bf(v.x - bf2f(hv.x));
        hv.y = f2bf(v.y); lv.y = f2bf(v.y - bf2f(hv.y));
        hv.z = f2bf(v.z); lv.z = f2bf(v.z - bf2f(hv.z));
        hv.w = f2bf(v.w); lv.w = f2bf(v.w - bf2f(hv.w));
        *(ushort4*)(pwH + base) = hv;
        *(ushort4*)(pwL + base) = lv;
    } else {
        if (!splitText) return;
        long base = (long)(bid - 5680) * 1024 + t * 4;
        float4 v = *(const float4*)(text + base);
        ushort4 hv;
        hv.x = f2bf(v.x);
        hv.y = f2bf(v.y);
        hv.z = f2bf(v.z);
        hv.w = f2bf(v.w);
        *(ushort4*)(textH + base) = hv;
    }
}

// combT[k][j][h] = sum_m WsT[k][j][m] * pw[k][h][m], split-bf16 3-MFMA.
__global__ __launch_bounds__(256) void comb_mfma_kernel(
    const u16* __restrict__ WsTH, const u16* __restrict__ WsTL,
    const u16* __restrict__ pwH, const u16* __restrict__ pwL,
    u16* __restrict__ combTH, u16* __restrict__ combTL)
{
    __shared__ __align__(16) u16 AsH[128 * 32];
    __shared__ __align__(16) u16 AsL[128 * 32];
    __shared__ __align__(16) u16 BsH[128 * 32];
    __shared__ __align__(16) u16 BsL[128 * 32];
    const int t = threadIdx.x;
    const int wave = t >> 6, lane = t & 63;
    const int k = blockIdx.z;
    const long m0 = (long)blockIdx.x * 128;   // j-rows
    const int n0 = blockIdx.y * 128;          // h-cols
    const u16* AH = WsTH + (long)k * HH;
    const u16* AL = WsTL + (long)k * HH;
    const u16* BH = pwH + (long)k * HH;
    const u16* BL = pwL + (long)k * HH;

    const int r = t >> 2, ch = t & 3;
    const int wm = (wave & 1) * 64, wn = (wave >> 1) * 64;
    const int fr = lane & 15, fq = lane >> 4;

    f32x4 acc[4][4];
    #pragma unroll
    for (int i = 0; i < 4; ++i)
        #pragma unroll
        for (int j = 0; j < 4; ++j) acc[i][j] = (f32x4){0.f, 0.f, 0.f, 0.f};

    for (int k0 = 0; k0 < NH; k0 += 32) {
        gld16(AH + (m0 + r)      * NH + k0 + ch*8, AsH + t*8);
        gld16(AH + (m0 + 64 + r) * NH + k0 + ch*8, AsH + 2048 + t*8);
        gld16(AL + (m0 + r)      * NH + k0 + ch*8, AsL + t*8);
        gld16(AL + (m0 + 64 + r) * NH + k0 + ch*8, AsL + 2048 + t*8);
        gld16(BH + (long)(n0 + r)      * NH + k0 + ch*8, BsH + t*8);
        gld16(BH + (long)(n0 + 64 + r) * NH + k0 + ch*8, BsH + 2048 + t*8);
        gld16(BL + (long)(n0 + r)      * NH + k0 + ch*8, BsL + t*8);
        gld16(BL + (long)(n0 + 64 + r) * NH + k0 + ch*8, BsL + 2048 + t*8);
        __syncthreads();
        bf16x8 afH[4], afL[4], bfH[4], bfL[4];
        #pragma unroll
        for (int i = 0; i < 4; ++i) {
            afH[i] = *(const bf16x8*)(AsH + (wm + i*16 + fr)*32 + fq*8);
            afL[i] = *(const bf16x8*)(AsL + (wm + i*16 + fr)*32 + fq*8);
            bfH[i] = *(const bf16x8*)(BsH + (wn + i*16 + fr)*32 + fq*8);
            bfL[i] = *(const bf16x8*)(BsL + (wn + i*16 + fr)*32 + fq*8);
        }
        #pragma unroll
        for (int i = 0; i < 4; ++i)
            #pragma unroll
            for (int j = 0; j < 4; ++j) {
                acc[i][j] = __builtin_amdgcn_mfma_f32_16x16x32_bf16(afH[i], bfH[j], acc[i][j], 0, 0, 0);
                acc[i][j] = __builtin_amdgcn_mfma_f32_16x16x32_bf16(afH[i], bfL[j], acc[i][j], 0, 0, 0);
                acc[i][j] = __builtin_amdgcn_mfma_f32_16x16x32_bf16(afL[i], bfH[j], acc[i][j], 0, 0, 0);
            }
        __syncthreads();
    }
    long kb = (long)k * HH;
    #pragma unroll
    for (int i = 0; i < 4; ++i) {
        long m = m0 + wm + i*16 + fq*4;       // j-row
        #pragma unroll
        for (int j = 0; j < 4; ++j) {
            long n = n0 + wn + j*16 + fr;     // h-col
            #pragma unroll
            for (int rr = 0; rr < 4; ++rr) {
                float v = acc[i][j][rr];
                u16 hv = f2bf(v);
                u16 lv = f2bf(v - bf2f(hv));
                combTH[kb + (m + rr) * NH + n] = hv;
                combTL[kb + (m + rr) * NH + n] = lv;
            }
        }
    }
}

// tier 0/1: comb[k][h][j] f32 VALU GEMM (proven R8 kernel).
__global__ __launch_bounds__(256) void comb_valu_kernel(
    const float* __restrict__ pwW, const float* __restrict__ WsW,
    float* __restrict__ comb)
{
    __shared__ float AtT[32][68];
    __shared__ float Bt[32][132];
    const int t = threadIdx.x;
    const int m0 = blockIdx.x * 64, j0 = blockIdx.y * 128, k = blockIdx.z;
    const float* A = pwW + (long)k * HH;
    const float* B = WsW + (long)k * HH;
    const int r4 = (t >> 4) * 4, c8 = (t & 15) * 8;
    float acc[4][8];
    #pragma unroll
    for (int rr = 0; rr < 4; ++rr)
        #pragma unroll
        for (int cc = 0; cc < 8; ++cc) acc[rr][cc] = 0.f;
    for (int h0 = 0; h0 < NH; h0 += 32) {
        #pragma unroll
        for (int p = 0; p < 8; ++p) {
            int idx = p * 256 + t;
            int r = idx >> 5, hh = idx & 31;
            AtT[hh][r] = A[(long)(m0 + r) * NH + h0 + hh];
        }
        #pragma unroll
        for (int p = 0; p < 16; ++p) {
            int idx = p * 256 + t;
            int hh = idx >> 7, c = idx & 127;
            Bt[hh][c] = B[(long)(h0 + hh) * NH + j0 + c];
        }
        __syncthreads();
        for (int hh = 0; hh < 32; ++hh) {
            float4 av  = *(const float4*)&AtT[hh][r4];
            float4 bv0 = *(const float4*)&Bt[hh][c8];
            float4 bv1 = *(const float4*)&Bt[hh][c8 + 4];
            float a[4] = {av.x, av.y, av.z, av.w};
            float bb[8] = {bv0.x, bv0.y, bv0.z, bv0.w, bv1.x, bv1.y, bv1.z, bv1.w};
            #pragma unroll
            for (int rr = 0; rr < 4; ++rr)
                #pragma unroll
                for (int cc = 0; cc < 8; ++cc) acc[rr][cc] += a[rr] * bb[cc];
        }
        __syncthreads();
    }
    float* C = comb + (long)k * HH;
    #pragma unroll
    for (int rr = 0; rr < 4; ++rr)
        #pragma unroll
        for (int cc = 0; cc < 8; ++cc)
            C[(long)(m0 + r4 + rr) * NH + j0 + c8 + cc] = acc[rr][cc];
}

// tier1: transpose+split comb f32 -> combTH/combTL. grid 2304.
__global__ void split_combT_kernel(const float* __restrict__ comb,
                                   u16* __restrict__ combTH, u16* __restrict__ combTL)
{
    __shared__ float tile[32][33];
    int bid = blockIdx.x, t = threadIdx.x;
    int k = bid / 576, rem = bid % 576, tr = rem / 24, tc = rem % 24;
    const float* src = comb + (long)k * HH;
    long dbase = (long)k * HH;
    int tx = t & 31, ty = t >> 5;
    #pragma unroll
    for (int i = 0; i < 4; ++i)
        tile[tx][ty + i*8] = src[(long)(tr*32 + ty + i*8) * NH + tc*32 + tx];
    __syncthreads();
    #pragma unroll
    for (int i = 0; i < 4; ++i) {
        float v = tile[ty + i*8][tx];
        u16 hv = f2bf(v);
        u16 lv = f2bf(v - bf2f(hv));
        long o = dbase + (long)(tc*32 + ty + i*8) * NH + tr*32 + tx;
        combTH[o] = hv; combTL[o] = lv;
    }
}

// TIER3: TP[k][bs][j] = bf16((text @ comb[k])[bs][j]) for heads [0, NSTORE).
// BK=64 (12 barrier-pairs; 48 KB LDS keeps 3 blocks/CU). AM=1: A hi via
// gld16 from textH. B split hi/lo (2 MFMA). grid (128, 6, NSTORE).
template <int AM>
__global__ __launch_bounds__(256) void tp_gemm_kernel(
    const float* __restrict__ textf, const u16* __restrict__ textH,
    const u16* __restrict__ combTH, const u16* __restrict__ combTL,
    u16* __restrict__ TP)
{
    __shared__ __align__(16) u16 AsH[128 * 64];
    __shared__ __align__(16) u16 BsH[128 * 64];
    __shared__ __align__(16) u16 BsL[128 * 64];
    const int t = threadIdx.x;
    const int wave = t >> 6, lane = t & 63;
    const int k = blockIdx.z;
    const long m0 = (long)blockIdx.x * 128;   // bs-rows
    const int n0 = blockIdx.y * 128;          // j-cols
    const u16* BH = combTH + (long)k * HH;
    const u16* BL = combTL + (long)k * HH;

    const int r = t >> 3, ch = t & 7;         // 32 rows x 8 chunks per gld16 call
    const int wm = (wave & 1) * 64, wn = (wave >> 1) * 64;
    const int fr = lane & 15, fq = lane >> 4;

    f32x4 acc[4][4];
    #pragma unroll
    for (int i = 0; i < 4; ++i)
        #pragma unroll
        for (int j = 0; j < 4; ++j) acc[i][j] = (f32x4){0.f, 0.f, 0.f, 0.f};

    for (int h0 = 0; h0 < NH; h0 += 64) {
        if (AM) {
            #pragma unroll
            for (int q = 0; q < 4; ++q)
                gld16(textH + (m0 + q*32 + r) * NH + h0 + ch*8, AsH + q*2048 + t*8);
        } else {
            #pragma unroll
            for (int p = 0; p < 8; ++p) {
                int task = p * 256 + t;
                int row = task >> 4, g = task & 15;
                float4 v = *(const float4*)(textf + (m0 + row) * NH + h0 + g*4);
                ushort4 hv;
                hv.x = f2bf(v.x);
                hv.y = f2bf(v.y);
                hv.z = f2bf(v.z);
                hv.w = f2bf(v.w);
                *(ushort4*)(AsH + row * 64 + g*4) = hv;
            }
        }
        #pragma unroll
        for (int q = 0; q < 4; ++q) {
            gld16(BH + (long)(n0 + q*32 + r) * NH + h0 + ch*8, BsH + q*2048 + t*8);
            gld16(BL + (long)(n0 + q*32 + r) * NH + h0 + ch*8, BsL + q*2048 + t*8);
        }
        __syncthreads();
        #pragma unroll
        for (int ks = 0; ks < 2; ++ks) {
            bf16x8 afH[4], bfH[4], bfL[4];
            #pragma unroll
            for (int i = 0; i < 4; ++i) {
                afH[i] = *(const bf16x8*)(AsH + (wm + i*16 + fr)*64 + ks*32 + fq*8);
                bfH[i] = *(const bf16x8*)(BsH + (wn + i*16 + fr)*64 + ks*32 + fq*8);
                bfL[i] = *(const bf16x8*)(BsL + (wn + i*16 + fr)*64 + ks*32 + fq*8);
            }
            #pragma unroll
            for (int i = 0; i < 4; ++i)
                #pragma unroll
                for (int j = 0; j < 4; ++j) {
                    acc[i][j] = __builtin_amdgcn_mfma_f32_16x16x32_bf16(afH[i], bfH[j], acc[i][j], 0, 0, 0);
                    acc[i][j] = __builtin_amdgcn_mfma_f32_16x16x32_bf16(afH[i], bfL[j], acc[i][j], 0, 0, 0);
                }
        }
        __syncthreads();
    }
    u16* out = TP + ((long)k * NBS + m0) * NH + n0;
    #pragma unroll
    for (int i = 0; i < 4; ++i) {
        #pragma unroll
        for (int rr = 0; rr < 4; ++rr) {
            int m = wm + i*16 + fq*4 + rr;
            #pragma unroll
            for (int j = 0; j < 4; ++j) {
                int n = wn + j*16 + fr;
                out[(long)m * NH + n] = f2bf(acc[i][j][rr]);
            }
        }
    }
}

// All hops: scores[k][b][s] = We_b[k] + sum_j tanh(TP + W_ht)*We for stored
// heads (writes '='). 64 rows/block (logic verified in R11's passing run).
// grid (8, 32, NSTORE).
__global__ __launch_bounds__(256) void score_pass_kernel(
    const u16* __restrict__ TP, const float* __restrict__ W_ht,
    const float* __restrict__ WeW, const float* __restrict__ Web,
    float* __restrict__ scores)
{
    __shared__ __align__(16) float bias_s[NH];
    __shared__ __align__(16) float we_s[NH];
    const int t = threadIdx.x;
    const int k = blockIdx.z, b = blockIdx.y;
    const int s0 = blockIdx.x * 64;
    for (int i = t; i < NH; i += 256) {
        bias_s[i] = W_ht[((k << 5) + b) * NH + i];
        we_s[i]   = WeW[k * NH + i];
    }
    __syncthreads();
    const int wave = t >> 6, lane = t & 63;
    const u16* tpb = TP + ((long)k * NBS + (b << 9) + s0) * NH;
    const float web = Web[k];
    for (int sr = wave; sr < 64; sr += 4) {
        const u16* row = tpb + (long)sr * NH;
        float part = 0.f;
        #pragma unroll
        for (int p = 0; p < 3; ++p) {
            const int j = p * 256 + lane * 4;   // 8B/lane bf16 loads, coalesced 512B
            ushort4 v = *(const ushort4*)(row + j);
            float4 bb = *(const float4*)(bias_s + j);
            float4 ww = *(const float4*)(we_s + j);
            part += tanh_fast(bf2f(v.x) + bb.x) * ww.x;
            part += tanh_fast(bf2f(v.y) + bb.y) * ww.y;
            part += tanh_fast(bf2f(v.z) + bb.z) * ww.z;
            part += tanh_fast(bf2f(v.w) + bb.w) * ww.w;
        }
        part += __shfl_xor(part, 1);
        part += __shfl_xor(part, 2);
        part += __shfl_xor(part, 4);
        part += __shfl_xor(part, 8);
        part += __shfl_xor(part, 16);
        part += __shfl_xor(part, 32);
        if (lane == 0) scores[(((k << 5) + b) << 9) + s0 + sr] = part + web;
    }
}

// scores = We_b for heads [koff, NK) (ahead of atomicAdd fused path).
__global__ void init_scores_kernel(const float* __restrict__ Web,
                                   float* __restrict__ scores, int koff)
{
    int idx = (koff << 14) + blockIdx.x * 256 + threadIdx.x;
    scores[idx] = Web[idx >> 14];
}

// W_ht[k][b][j] = Wtb + combB + q.Wt  (full dot, no atomics). grid 384.
__global__ __launch_bounds__(256) void wht2_kernel(
    const float* __restrict__ q, const float* __restrict__ WtW,
    const float* __restrict__ combB, const float* __restrict__ Wtb,
    float* __restrict__ W_ht)
{
    int bid = blockIdx.x;                 // 4k x 32b x 3jt
    int k = bid / 96, rem = bid % 96, b = rem / 3, jt = rem % 3;
    int j = jt * 256 + threadIdx.x;
    const float* W = WtW + (long)k * HH + j;
    const float* qb = q + b * NH;
    float acc = 0.f;
    #pragma unroll 8
    for (int h = 0; h < NH; ++h) acc += qb[h] * W[(long)h * NH];
    W_ht[(k*NB + b) * NH + j] = acc + Wtb[k * NH + j] + combB[k * NH + j];
}

// ---------------------------------------------------------------------------
// MFMA split-bf16 fused scores (W_ht includes combB), head-offset koff.
// grid (128, 6, nheads).
// ---------------------------------------------------------------------------
template <int AM>
__global__ __launch_bounds__(256) void fused_scores_mfma(
    const float* __restrict__ textf,
    const u16* __restrict__ textH, const u16* __restrict__ textL,
    const u16* __restrict__ combTH, const u16* __restrict__ combTL,
    const float* __restrict__ W_ht,
    const float* __restrict__ WeW, float* __restrict__ scores, int koff)
{
    __shared__ __align__(16) u16 AsH[128 * 32];
    __shared__ __align__(16) u16 AsL[128 * 32];
    __shared__ __align__(16) u16 BsH[128 * 32];
    __shared__ __align__(16) u16 BsL[128 * 32];
    __shared__ float wht_s[128];
    __shared__ float we_s[128];
    __shared__ float sred[128];
    const int t = threadIdx.x;
    const int wave = t >> 6, lane = t & 63;
    const int k = koff + blockIdx.z;
    const long m0 = (long)blockIdx.x * 128;
    const int n0 = blockIdx.y * 128;
    const int b = (int)(m0 >> 9), srow = (int)(m0 & 511);
    const u16* BH = combTH + (long)k * HH;
    const u16* BL = combTL + (long)k * HH;

    if (t < 128) {
        wht_s[t] = W_ht[((k << 5) + b) * NH + n0 + t];
        we_s[t]  = WeW[k * NH + n0 + t];
        sred[t]  = 0.f;
    }

    const int r = t >> 2, ch = t & 3;
    const int wm = (wave & 1) * 64, wn = (wave >> 1) * 64;
    const int fr = lane & 15, fq = lane >> 4;

    f32x4 acc[4][4];
    #pragma unroll
    for (int i = 0; i < 4; ++i)
        #pragma unroll
        for (int j = 0; j < 4; ++j) acc[i][j] = (f32x4){0.f, 0.f, 0.f, 0.f};

    for (int h0 = 0; h0 < NH; h0 += 32) {
        if (AM) {
            gld16(textH + (m0 + r)      * NH + h0 + ch*8, AsH + t*8);
            gld16(textH + (m0 + 64 + r) * NH + h0 + ch*8, AsH + 2048 + t*8);
            gld16(textL + (m0 + r)      * NH + h0 + ch*8, AsL + t*8);
            gld16(textL + (m0 + 64 + r) * NH + h0 + ch*8, AsL + 2048 + t*8);
        } else {
            #pragma unroll
            for (int p = 0; p < 4; ++p) {
                int task = p * 256 + t;
                int row = task >> 3, g = task & 7;
                float4 v = *(const float4*)(textf + (m0 + row) * NH + h0 + g*4);
                ushort4 hv, lv;
                hv.x = f2bf(v.x); lv.x = f2bf(v.x - bf2f(hv.x));
                hv.y = f2bf(v.y); lv.y = f2bf(v.y - bf2f(hv.y));
                hv.z = f2bf(v.z); lv.z = f2bf(v.z - bf2f(hv.z));
                hv.w = f2bf(v.w); lv.w = f2bf(v.w - bf2f(hv.w));
                *(ushort4*)(AsH + row * 32 + g*4) = hv;
                *(ushort4*)(AsL + row * 32 + g*4) = lv;
            }
        }
        gld16(BH + (long)(n0 + r)      * NH + h0 + ch*8, BsH + t*8);
        gld16(BH + (long)(n0 + 64 + r) * NH + h0 + ch*8, BsH + 2048 + t*8);
        gld16(BL + (long)(n0 + r)      * NH + h0 + ch*8, BsL + t*8);
        gld16(BL + (long)(n0 + 64 + r) * NH + h0 + ch*8, BsL + 2048 + t*8);
        __syncthreads();
        bf16x8 afH[4], afL[4], bfH[4], bfL[4];
        #pragma unroll
        for (int i = 0; i < 4; ++i) {
            afH[i] = *(const bf16x8*)(AsH + (wm + i*16 + fr)*32 + fq*8);
            afL[i] = *(const bf16x8*)(AsL + (wm + i*16 + fr)*32 + fq*8);
            bfH[i] = *(const bf16x8*)(BsH + (wn + i*16 + fr)*32 + fq*8);
            bfL[i] = *(const bf16x8*)(BsL + (wn + i*16 + fr)*32 + fq*8);
        }
        #pragma unroll
        for (int i = 0; i < 4; ++i)
            #pragma unroll
            for (int j = 0; j < 4; ++j) {
                acc[i][j] = __builtin_amdgcn_mfma_f32_16x16x32_bf16(afH[i], bfH[j], acc[i][j], 0, 0, 0);
                acc[i][j] = __builtin_amdgcn_mfma_f32_16x16x32_bf16(afH[i], bfL[j], acc[i][j], 0, 0, 0);
                acc[i][j] = __builtin_amdgcn_mfma_f32_16x16x32_bf16(afL[i], bfH[j], acc[i][j], 0, 0, 0);
            }
        __syncthreads();
    }
    #pragma unroll
    for (int i = 0; i < 4; ++i) {
        #pragma unroll
        for (int rr = 0; rr < 4; ++rr) {
            int m = wm + i*16 + fq*4 + rr;
            float part = 0.f;
            #pragma unroll
            for (int j = 0; j < 4; ++j) {
                int n = wn + j*16 + fr;
                part += tanh_fast(acc[i][j][rr] + wht_s[n]) * we_s[n];
            }
            part += __shfl_xor(part, 1);
            part += __shfl_xor(part, 2);
            part += __shfl_xor(part, 4);
            part += __shfl_xor(part, 8);
            if (fr == 0) atomicAdd(&sred[m], part);
        }
    }
    __syncthreads();
    if (t < 128)
        atomicAdd(&scores[(((k << 5) + b) << 9) + srow + t], sred[t]);
}

// tier0 fallback (W_ht includes combB). grid (256, 6, 4).
__global__ __launch_bounds__(256) void fused_scores_valu(
    const float* __restrict__ text, const float* __restrict__ comb,
    const float* __restrict__ W_ht,
    const float* __restrict__ WeW, float* __restrict__ scores)
{
    __shared__ float AtT[32][68];
    __shared__ float Bt[32][132];
    __shared__ float wht_s[128];
    __shared__ float we_s[128];
    __shared__ float sred[64];
    const int t = threadIdx.x;
    const int row0 = blockIdx.x * 64;
    const int j0 = blockIdx.y * 128, k = blockIdx.z;
    const int b = row0 >> 9, s0 = row0 & 511;
    const float* B = comb + (long)k * HH;
    const int r4 = (t >> 4) * 4, c8 = (t & 15) * 8;
    if (t < 128) {
        wht_s[t] = W_ht[((k << 5) + b) * NH + j0 + t];
        we_s[t]  = WeW[k * NH + j0 + t];
    }
    if (t < 64) sred[t] = 0.f;
    float acc[4][8];
    #pragma unroll
    for (int rr = 0; rr < 4; ++rr)
        #pragma unroll
        for (int cc = 0; cc < 8; ++cc) acc[rr][cc] = 0.f;
    for (int h0 = 0; h0 < NH; h0 += 32) {
        #pragma unroll
        for (int p = 0; p < 8; ++p) {
            int idx = p * 256 + t;
            int r = idx >> 5, hh = idx & 31;
            AtT[hh][r] = text[(long)(row0 + r) * NH + h0 + hh];
        }
        #pragma unroll
        for (int p = 0; p < 16; ++p) {
            int idx = p * 256 + t;
            int hh = idx >> 7, c = idx & 127;
            Bt[hh][c] = B[(long)(h0 + hh) * NH + j0 + c];
        }
        __syncthreads();
        for (int hh = 0; hh < 32; ++hh) {
            float4 av  = *(const float4*)&AtT[hh][r4];
            float4 bv0 = *(const float4*)&Bt[hh][c8];
            float4 bv1 = *(const float4*)&Bt[hh][c8 + 4];
            float a[4] = {av.x, av.y, av.z, av.w};
            float bb[8] = {bv0.x, bv0.y, bv0.z, bv0.w, bv1.x, bv1.y, bv1.z, bv1.w};
            #pragma unroll
            for (int rr = 0; rr < 4; ++rr)
                #pragma unroll
                for (int cc = 0; cc < 8; ++cc) acc[rr][cc] += a[rr] * bb[cc];
        }
        __syncthreads();
    }
    float part[4] = {0.f, 0.f, 0.f, 0.f};
    #pragma unroll
    for (int rr = 0; rr < 4; ++rr)
        #pragma unroll
        for (int cc = 0; cc < 8; ++cc)
            part[rr] += tanh_fast(acc[rr][cc] + wht_s[c8 + cc]) * we_s[c8 + cc];
    #pragma unroll
    for (int rr = 0; rr < 4; ++rr)
        atomicAdd(&sred[r4 + rr], part[rr]);
    __syncthreads();
    if (t < 64)
        atomicAdd(&scores[(((k << 5) + b) << 9) + s0 + t], sred[t]);
}

// Shuffle-based softmax + head-combine + argmax + xT build. grid 32.
__global__ void softmax_kernel(const float* __restrict__ scores,
                               const float* __restrict__ headw_W, const float* __restrict__ headw_b,
                               const float* __restrict__ text,
                               const float* __restrict__ q_f32,
                               float* __restrict__ xT, float* __restrict__ out_prob, int hop)
{
    __shared__ float sc[NK][NS];
    __shared__ float cred[4];
    __shared__ float cval[4];
    __shared__ int   cidx[4];
    int b = blockIdx.x, t = threadIdx.x;
    int wave = t >> 6, lane = t & 63;
    for (int i = t; i < NK * NS; i += 256) {
        int k = i >> 9, s = i & 511;
        sc[k][s] = scores[((k*NB + b) << 9) + s];
    }
    __syncthreads();
    float fac[NK];
    for (int k = 0; k < NK; ++k) {
        float v0 = sc[k][t], v1 = sc[k][t + 256];
        float m = fmaxf(v0, v1);
        #pragma unroll
        for (int o = 32; o > 0; o >>= 1) m = fmaxf(m, __shfl_xor(m, o));
        if (lane == 0) cred[wave] = m;
        __syncthreads();
        float mx = fmaxf(fmaxf(cred[0], cred[1]), fmaxf(cred[2], cred[3]));
        __syncthreads();
        float e0 = __expf(v0 - mx), e1 = __expf(v1 - mx);
        sc[k][t] = e0; sc[k][t + 256] = e1;
        float sm = e0 + e1;
        #pragma unroll
        for (int o = 32; o > 0; o >>= 1) sm += __shfl_xor(sm, o);
        if (lane == 0) cred[wave] = sm;
        __syncthreads();
        fac[k] = headw_W[k] / (cred[0] + cred[1] + cred[2] + cred[3]);
        __syncthreads();
    }
    float hwb = headw_b[0];
    float a0 = hwb, a1 = hwb;
    for (int k = 0; k < NK; ++k) { a0 += sc[k][t] * fac[k]; a1 += sc[k][t + 256] * fac[k]; }
    float ss = a0*a0 + a1*a1;
    #pragma unroll
    for (int o = 32; o > 0; o >>= 1) ss += __shfl_xor(ss, o);
    float bv; int bi;
    if (a0 >= a1) { bv = a0; bi = t; } else { bv = a1; bi = t + 256; }
    #pragma unroll
    for (int o = 1; o < 64; o <<= 1) {
        float ov = __shfl_xor(bv, o);
        int   oi = __shfl_xor(bi, o);
        if (ov > bv || (ov == bv && oi < bi)) { bv = ov; bi = oi; }
    }
    if (lane == 0) { cred[wave] = ss; cval[wave] = bv; cidx[wave] = bi; }
    __syncthreads();
    float scale = sqrtf(cred[0] + cred[1] + cred[2] + cred[3]);
    float mbv = cval[0]; int mbi = cidx[0];
    #pragma unroll
    for (int w = 1; w < 4; ++w)
        if (cval[w] > mbv || (cval[w] == mbv && cidx[w] < mbi)) { mbv = cval[w]; mbi = cidx[w]; }
    int idx = mbi;
    if (hop == 0) {
        out_prob[(b << 9) + t]       = a0 / scale;
        out_prob[(b << 9) + t + 256] = a1 / scale;
    }
    const float* trow = text + (long)(b * NS + idx) * NH;
    for (int i = t; i < NH; i += 256) {
        xT[i * NB + b]        = q_f32[b*NH + i];
        xT[(NH + i) * NB + b] = trow[i];
    }
}

// GRU matvec partials: grid (36 j-tiles, 9 chunks: 6 sx + 3 sh); atomicAdd.
__global__ __launch_bounds__(256) void gru_mm3_kernel(
    const float* __restrict__ Wih, const float* __restrict__ Whh,
    const float* __restrict__ xT, const float* __restrict__ hT,
    float* __restrict__ sx, float* __restrict__ sh)
{
    __shared__ float xs[8192];
    int t = threadIdx.x;
    int tj = t & 63, tq = t >> 6;
    int j = blockIdx.x * 64 + tj;
    int cgi = blockIdx.y;
    const float* W; const float* src; float* dst; int c;
    if (cgi < 6) { W = Wih; src = xT; dst = sx; c = cgi; }
    else         { W = Whh; src = hT; dst = sh; c = cgi - 6; }
    for (int idx = t; idx < 8192; idx += 256) xs[idx] = src[c * 8192 + idx];
    __syncthreads();
    float acc[8];
    #pragma unroll
    for (int bq = 0; bq < 8; ++bq) acc[bq] = 0.f;
    #pragma unroll 8
    for (int ii = 0; ii < 256; ++ii) {
        float w = W[(long)(c * 256 + ii) * H3 + j];
        #pragma unroll
        for (int bq = 0; bq < 8; ++bq) acc[bq] += xs[ii * 32 + tq * 8 + bq] * w;
    }
    #pragma unroll
    for (int bq = 0; bq < 8; ++bq)
        atomicAdd(&dst[(long)(tq * 8 + bq) * H3 + j], acc[bq]);
}

// Gate + h/q update; re-zeroes sx/sh for the next hop after reading.
__global__ void gate_kernel(const float* __restrict__ bih, const float* __restrict__ bhh,
                            float* __restrict__ sx, float* __restrict__ sh,
                            float* __restrict__ hT, float* __restrict__ q_f32,
                            float* __restrict__ out_h, int hop)
{
    int gid = blockIdx.x * 256 + threadIdx.x;
    int b = gid / NH, j = gid % NH;
    float xr = bih[j]        + sx[b*H3 + j];
    float xz = bih[NH + j]   + sx[b*H3 + NH + j];
    float xn = bih[1536 + j] + sx[b*H3 + 1536 + j];
    float hr = bhh[j]        + sh[b*H3 + j];
    float hz = bhh[NH + j]   + sh[b*H3 + NH + j];
    float hn = bhh[1536 + j] + sh[b*H3 + 1536 + j];
    sx[b*H3 + j] = 0.f; sx[b*H3 + NH + j] = 0.f; sx[b*H3 + 1536 + j] = 0.f;
    sh[b*H3 + j] = 0.f; sh[b*H3 + NH + j] = 0.f; sh[b*H3 + 1536 + j] = 0.f;
    float r = sig_fast(xr + hr);
    float z = sig_fast(xz + hz);
    float n = tanh_fast(xn + r * hn);
    float hp = hT[j * NB + b];
    float hnew = (1.f - z) * n + z * hp;
    hT[j * NB + b] = hnew;
    q_f32[gid] = hnew;
    out_h[(long)(b * 3 + hop) * NH + j] = hnew;
}

// ---------------------------------------------------------------------------
extern "C" void kernel_launch(void* const* d_in, const int* in_sizes, int n_in,
                              void* d_out, int out_size, void* d_ws, size_t ws_size,
                              hipStream_t stream)
{
    const float* question = (const float*)d_in[0];
    const float* text     = (const float*)d_in[1];
    const float* pw_W     = (const float*)d_in[2];
    const float* pw_b     = (const float*)d_in[3];
    const float* Ws_W     = (const float*)d_in[4];
    const float* Ws_b     = (const float*)d_in[5];
    const float* Wt_W     = (const float*)d_in[6];
    const float* Wt_b     = (const float*)d_in[7];
    const float* We_W     = (const float*)d_in[8];
    const float* We_b     = (const float*)d_in[9];
    const float* headw_W  = (const float*)d_in[10];
    const float* headw_b  = (const float*)d_in[11];
    const float* Wih      = (const float*)d_in[12];
    const float* Whh      = (const float*)d_in[13];
    const float* bih      = (const float*)d_in[14];
    const float* bhh      = (const float*)d_in[15];

    char* ws = (char*)d_ws;
    float* comb   = (float*)(ws + 0);
    float* combB  = (float*)(ws + 9437184);
    float* W_ht   = (float*)(ws + 9449472);
    float* scores = (float*)(ws + 9842688);
    float* q_f32  = (float*)(ws + 10104832);
    float* hT     = (float*)(ws + 10203136);
    float* xT     = (float*)(ws + 10301440);
    float* sx     = (float*)(ws + 10498048);
    float* sh     = (float*)(ws + 10792960);
    u16*   combTH = (u16*)  (ws + 11087872);
    u16*   combTL = (u16*)  (ws + 15806464);
    u16*   TP     = (u16*)  (ws + 20525056);
    u16*   textH  = (u16*)  (ws + 121188352);
    // prep scratch overlaid on TP region (dead before tp_gemm runs):
    u16*   WsTH   = (u16*)  (ws + 20525056);
    u16*   WsTL   = (u16*)  (ws + 25243648);
    u16*   pwH    = (u16*)  (ws + 29962240);
    u16*   pwL    = (u16*)  (ws + 34680832);

    int nstore = 0;
    if (ws_size >= (size_t)70856704) {
        long avail = (long)ws_size - 20525056L;
        nstore = (int)(avail / 25165824L);
        if (nstore > NK) nstore = NK;
    }
    const int tier = (nstore >= 1) ? 3
                   : (ws_size >= (size_t)20525056) ? 1 : 0;
    const bool haveTextH = (tier == 3) && (nstore == NK)
                        && (ws_size >= (size_t)146354176);

    float* out_prob = (float*)d_out;
    float* out_h    = (float*)d_out + NB * NS;

    const int prepGrid = haveTextH ? 17968 : (tier >= 2 ? 5680 : 1072);
    prep_kernel<<<prepGrid, 256, 0, stream>>>(
        Ws_W, pw_b, Ws_b, combB, question, q_f32, hT, sx, sh, We_b, scores,
        pw_W, WsTH, WsTL, pwH, pwL, text, textH,
        tier >= 3 ? 2 : tier, haveTextH ? 1 : 0);

    if (tier == 3) {
        comb_mfma_kernel<<<dim3(6, 6, 4), 256, 0, stream>>>(WsTH, WsTL, pwH, pwL,
                                                            combTH, combTL);
        // scratch dead from here; TP overwrites it.
        if (haveTextH) {
            tp_gemm_kernel<1><<<dim3(128, 6, nstore), 256, 0, stream>>>(
                text, textH, combTH, combTL, TP);
        } else {
            tp_gemm_kernel<0><<<dim3(128, 6, nstore), 256, 0, stream>>>(
                text, nullptr, combTH, combTL, TP);
        }
    } else {
        comb_valu_kernel<<<dim3(12, 6, 4), 256, 0, stream>>>(pw_W, Ws_W, comb);
        if (tier == 1)
            split_combT_kernel<<<2304, 256, 0, stream>>>(comb, combTH, combTL);
    }

    for (int hop = 0; hop < 3; ++hop) {
        wht2_kernel<<<384, 256, 0, stream>>>(q_f32, Wt_W, combB, Wt_b, W_ht);
        if (tier == 3) {
            score_pass_kernel<<<dim3(8, 32, nstore), 256, 0, stream>>>(
                TP, W_ht, We_W, We_b, scores);
            if (nstore < NK) {
                if (hop > 0)
                    init_scores_kernel<<<(NK - nstore) * 64, 256, 0, stream>>>(
                        We_b, scores, nstore);
                fused_scores_mfma<0><<<dim3(128, 6, NK - nstore), 256, 0, stream>>>(
                    text, nullptr, nullptr, combTH, combTL, W_ht, We_W,
                    scores, nstore);
            }
        } else if (tier == 1) {
            init_scores_kernel<<<256, 256, 0, stream>>>(We_b, scores, 0);
            fused_scores_mfma<0><<<dim3(128, 6, 4), 256, 0, stream>>>(
                text, nullptr, nullptr, combTH, combTL, W_ht, We_W, scores, 0);
        } else {
            init_scores_kernel<<<256, 256, 0, stream>>>(We_b, scores, 0);
            fused_scores_valu<<<dim3(256, 6, 4), 256, 0, stream>>>(
                text, comb, W_ht, We_W, scores);
        }
        softmax_kernel<<<32, 256, 0, stream>>>(scores, headw_W, headw_b, text,
                                               q_f32, xT, out_prob, hop);
        gru_mm3_kernel<<<dim3(36, 9), 256, 0, stream>>>(Wih, Whh, xT, hT, sx, sh);
        gate_kernel<<<96, 256, 0, stream>>>(bih, bhh, sx, sh, hT, q_f32, out_h, hop);
    }
}

// Round 13
// 577.496 us; speedup vs baseline: 4.2334x; 1.0984x over previous
//
#include <hip/hip_runtime.h>

typedef unsigned short u16;
typedef __bf16 bf16x8 __attribute__((ext_vector_type(8)));
typedef float f32x4 __attribute__((ext_vector_type(4)));

#define NB 32          // batch
#define NS 512         // seq
#define NH 768         // hidden
#define NK 4           // heads
#define NBS 16384      // B*S
#define H3 2304        // 3H
#define HH 589824      // 768*768

__device__ inline float bf2f(u16 u) {
    unsigned x = ((unsigned)u) << 16;
    return __builtin_bit_cast(float, x);
}
__device__ inline u16 f2bf(float f) {
    unsigned u = __builtin_bit_cast(unsigned, f);
    u += 0x7fffu + ((u >> 16) & 1u);
    return (u16)(u >> 16);
}
// fast tanh: 1 - 2*rcp(exp(2x)+1). ~5 VALU vs ~20+ for libm tanhf. err ~1e-6.
__device__ inline float tanh_fast(float x) {
    float e = __expf(2.f * x);
    return 1.f - 2.f * __builtin_amdgcn_rcpf(e + 1.f);
}
__device__ inline float sig_fast(float x) {
    return __builtin_amdgcn_rcpf(1.f + __expf(-x));
}
// async global->LDS, 16B/lane; LDS dst = wave-uniform base + lane*16 (m97 recipe).
__device__ inline void gld16(const u16* g, u16* l) {
    __builtin_amdgcn_global_load_lds(
        (const __attribute__((address_space(1))) unsigned int*)g,
        (__attribute__((address_space(3))) unsigned int*)l, 16, 0, 0);
}

// ---------------------------------------------------------------------------
// Workspace layout (bytes): unchanged from R9/R12.
//  comb @ 0 | combB @ 9,437,184 | W_ht @ 9,449,472 | scores @ 9,842,688
//  q_f32 @ 10,104,832 | hT @ 10,203,136 | xT @ 10,301,440
//  sx @ 10,498,048 | sh @ 10,792,960 | combTH @ 11,087,872 | combTL @ 15,806,464
//  TP @ 20,525,056 (NSTORE x 25,165,824 bf16) | textH @ 121,188,352
//  prep scratch overlaid on TP: WsTH/WsTL/pwH/pwL.
//
// R13: drop the B-lo (combTL) MFMA term from tp_gemm. TP is stored in bf16;
// the B-lo contribution (~1.2e-3 RMS over the 768-dot) is at TP's own
// storage-quantization level, so computing it is wasted work (same argument
// as R4's A-lo drop, which passed). MFMA count halves (64->32/K-iter),
// B staging halves, LDS 48->32 KB. Expected tp_gemm 172 -> ~115 us;
// absmax 0.00195 -> ~0.004. All other kernels byte-identical to R12
// (proven 634 us). combTL still produced (used by tier1/partial fallbacks).
// ---------------------------------------------------------------------------

// P: one-time prep. grid up to 17968 (sections gated).
__global__ void prep_kernel(const float* __restrict__ WsW, const float* __restrict__ pwb,
                            const float* __restrict__ Wsb, float* __restrict__ combB,
                            const float* __restrict__ question,
                            float* __restrict__ q_f32, float* __restrict__ hT,
                            float* __restrict__ sx, float* __restrict__ sh,
                            const float* __restrict__ Web, float* __restrict__ scores,
                            const float* __restrict__ pwW,
                            u16* __restrict__ WsTH, u16* __restrict__ WsTL,
                            u16* __restrict__ pwH, u16* __restrict__ pwL,
                            const float* __restrict__ text, u16* __restrict__ textH,
                            int tier, int splitText)
{
    int bid = blockIdx.x, t = threadIdx.x;
    if (bid < 48) {
        int idx = bid * 64 + (t >> 2);      // 0..3071
        int ph = t & 3;
        int k = idx / NH, j = idx % NH;
        const float* W = WsW + (long)k * HH + j;
        const float* pb = pwb + k * NH;
        float acc = 0.f;
        #pragma unroll 8
        for (int m = ph * 192; m < ph * 192 + 192; ++m)
            acc += pb[m] * W[(long)m * NH];
        acc += __shfl_xor(acc, 1);
        acc += __shfl_xor(acc, 2);
        if (ph == 0) combB[idx] = acc + Wsb[idx];
    } else if (bid < 144) {
        int idx = (bid - 48) * 256 + t;
        q_f32[idx] = question[idx];
    } else if (bid < 240) {
        int idx = (bid - 144) * 256 + t;
        hT[idx] = 0.f;
    } else if (bid < 816) {
        int idx = (bid - 240) * 256 + t;    // 147,456 floats
        if (idx < 73728) sx[idx] = 0.f;
        else sh[idx - 73728] = 0.f;
    } else if (bid < 1072) {
        int idx = (bid - 816) * 256 + t;    // 65,536: scores = We_b (hop 0,
        scores[idx] = Web[idx >> 14];       // needed for fused leftover heads)
    } else if (bid < 3376) {
        if (tier < 2) return;
        __shared__ float tile[32][33];
        int bid2 = bid - 1072;
        int k = bid2 / 576, rem = bid2 % 576, tr = rem / 24, tc = rem % 24;
        const float* src = WsW + (long)k * HH;
        long dbase = (long)k * HH;
        int tx = t & 31, ty = t >> 5;
        #pragma unroll
        for (int i = 0; i < 4; ++i)
            tile[tx][ty + i*8] = src[(long)(tr*32 + ty + i*8) * NH + tc*32 + tx];
        __syncthreads();
        #pragma unroll
        for (int i = 0; i < 4; ++i) {
            float v = tile[ty + i*8][tx];
            u16 hv = f2bf(v);
            u16 lv = f2bf(v - bf2f(hv));
            long o = dbase + (long)(tc*32 + ty + i*8) * NH + tr*32 + tx;
            WsTH[o] = hv; WsTL[o] = lv;
        }
    } else if (bid < 5680) {
        if (tier < 2) return;
        long base = (long)(bid - 3376) * 1024 + t * 4;
        float4 v = *(const float4*)(pwW + base);
        ushort4 hv, lv;
        hv.x = f2bf(v.x); lv.x = f2bf(v.x - bf2f(hv.x));
        hv.y = f2bf(v.y); lv.y = f2bf(v.y - bf2f(hv.y));
        hv.z = f2bf(v.z); lv.z = f2bf(v.z - bf2f(hv.z));
        hv.w = f2bf(v.w); lv.w = f2bf(v.w - bf2f(hv.w));
        *(ushort4*)(pwH + base) = hv;
        *(ushort4*)(pwL + base) = lv;
    } else {
        if (!splitText) return;
        long base = (long)(bid - 5680) * 1024 + t * 4;
        float4 v = *(const float4*)(text + base);
        ushort4 hv;
        hv.x = f2bf(v.x);
        hv.y = f2bf(v.y);
        hv.z = f2bf(v.z);
        hv.w = f2bf(v.w);
        *(ushort4*)(textH + base) = hv;
    }
}

// combT[k][j][h] = sum_m WsT[k][j][m] * pw[k][h][m], split-bf16 3-MFMA.
__global__ __launch_bounds__(256) void comb_mfma_kernel(
    const u16* __restrict__ WsTH, const u16* __restrict__ WsTL,
    const u16* __restrict__ pwH, const u16* __restrict__ pwL,
    u16* __restrict__ combTH, u16* __restrict__ combTL)
{
    __shared__ __align__(16) u16 AsH[128 * 32];
    __shared__ __align__(16) u16 AsL[128 * 32];
    __shared__ __align__(16) u16 BsH[128 * 32];
    __shared__ __align__(16) u16 BsL[128 * 32];
    const int t = threadIdx.x;
    const int wave = t >> 6, lane = t & 63;
    const int k = blockIdx.z;
    const long m0 = (long)blockIdx.x * 128;   // j-rows
    const int n0 = blockIdx.y * 128;          // h-cols
    const u16* AH = WsTH + (long)k * HH;
    const u16* AL = WsTL + (long)k * HH;
    const u16* BH = pwH + (long)k * HH;
    const u16* BL = pwL + (long)k * HH;

    const int r = t >> 2, ch = t & 3;
    const int wm = (wave & 1) * 64, wn = (wave >> 1) * 64;
    const int fr = lane & 15, fq = lane >> 4;

    f32x4 acc[4][4];
    #pragma unroll
    for (int i = 0; i < 4; ++i)
        #pragma unroll
        for (int j = 0; j < 4; ++j) acc[i][j] = (f32x4){0.f, 0.f, 0.f, 0.f};

    for (int k0 = 0; k0 < NH; k0 += 32) {
        gld16(AH + (m0 + r)      * NH + k0 + ch*8, AsH + t*8);
        gld16(AH + (m0 + 64 + r) * NH + k0 + ch*8, AsH + 2048 + t*8);
        gld16(AL + (m0 + r)      * NH + k0 + ch*8, AsL + t*8);
        gld16(AL + (m0 + 64 + r) * NH + k0 + ch*8, AsL + 2048 + t*8);
        gld16(BH + (long)(n0 + r)      * NH + k0 + ch*8, BsH + t*8);
        gld16(BH + (long)(n0 + 64 + r) * NH + k0 + ch*8, BsH + 2048 + t*8);
        gld16(BL + (long)(n0 + r)      * NH + k0 + ch*8, BsL + t*8);
        gld16(BL + (long)(n0 + 64 + r) * NH + k0 + ch*8, BsL + 2048 + t*8);
        __syncthreads();
        bf16x8 afH[4], afL[4], bfH[4], bfL[4];
        #pragma unroll
        for (int i = 0; i < 4; ++i) {
            afH[i] = *(const bf16x8*)(AsH + (wm + i*16 + fr)*32 + fq*8);
            afL[i] = *(const bf16x8*)(AsL + (wm + i*16 + fr)*32 + fq*8);
            bfH[i] = *(const bf16x8*)(BsH + (wn + i*16 + fr)*32 + fq*8);
            bfL[i] = *(const bf16x8*)(BsL + (wn + i*16 + fr)*32 + fq*8);
        }
        #pragma unroll
        for (int i = 0; i < 4; ++i)
            #pragma unroll
            for (int j = 0; j < 4; ++j) {
                acc[i][j] = __builtin_amdgcn_mfma_f32_16x16x32_bf16(afH[i], bfH[j], acc[i][j], 0, 0, 0);
                acc[i][j] = __builtin_amdgcn_mfma_f32_16x16x32_bf16(afH[i], bfL[j], acc[i][j], 0, 0, 0);
                acc[i][j] = __builtin_amdgcn_mfma_f32_16x16x32_bf16(afL[i], bfH[j], acc[i][j], 0, 0, 0);
            }
        __syncthreads();
    }
    long kb = (long)k * HH;
    #pragma unroll
    for (int i = 0; i < 4; ++i) {
        long m = m0 + wm + i*16 + fq*4;       // j-row
        #pragma unroll
        for (int j = 0; j < 4; ++j) {
            long n = n0 + wn + j*16 + fr;     // h-col
            #pragma unroll
            for (int rr = 0; rr < 4; ++rr) {
                float v = acc[i][j][rr];
                u16 hv = f2bf(v);
                u16 lv = f2bf(v - bf2f(hv));
                combTH[kb + (m + rr) * NH + n] = hv;
                combTL[kb + (m + rr) * NH + n] = lv;
            }
        }
    }
}

// tier 0/1: comb[k][h][j] f32 VALU GEMM (proven R8 kernel).
__global__ __launch_bounds__(256) void comb_valu_kernel(
    const float* __restrict__ pwW, const float* __restrict__ WsW,
    float* __restrict__ comb)
{
    __shared__ float AtT[32][68];
    __shared__ float Bt[32][132];
    const int t = threadIdx.x;
    const int m0 = blockIdx.x * 64, j0 = blockIdx.y * 128, k = blockIdx.z;
    const float* A = pwW + (long)k * HH;
    const float* B = WsW + (long)k * HH;
    const int r4 = (t >> 4) * 4, c8 = (t & 15) * 8;
    float acc[4][8];
    #pragma unroll
    for (int rr = 0; rr < 4; ++rr)
        #pragma unroll
        for (int cc = 0; cc < 8; ++cc) acc[rr][cc] = 0.f;
    for (int h0 = 0; h0 < NH; h0 += 32) {
        #pragma unroll
        for (int p = 0; p < 8; ++p) {
            int idx = p * 256 + t;
            int r = idx >> 5, hh = idx & 31;
            AtT[hh][r] = A[(long)(m0 + r) * NH + h0 + hh];
        }
        #pragma unroll
        for (int p = 0; p < 16; ++p) {
            int idx = p * 256 + t;
            int hh = idx >> 7, c = idx & 127;
            Bt[hh][c] = B[(long)(h0 + hh) * NH + j0 + c];
        }
        __syncthreads();
        for (int hh = 0; hh < 32; ++hh) {
            float4 av  = *(const float4*)&AtT[hh][r4];
            float4 bv0 = *(const float4*)&Bt[hh][c8];
            float4 bv1 = *(const float4*)&Bt[hh][c8 + 4];
            float a[4] = {av.x, av.y, av.z, av.w};
            float bb[8] = {bv0.x, bv0.y, bv0.z, bv0.w, bv1.x, bv1.y, bv1.z, bv1.w};
            #pragma unroll
            for (int rr = 0; rr < 4; ++rr)
                #pragma unroll
                for (int cc = 0; cc < 8; ++cc) acc[rr][cc] += a[rr] * bb[cc];
        }
        __syncthreads();
    }
    float* C = comb + (long)k * HH;
    #pragma unroll
    for (int rr = 0; rr < 4; ++rr)
        #pragma unroll
        for (int cc = 0; cc < 8; ++cc)
            C[(long)(m0 + r4 + rr) * NH + j0 + c8 + cc] = acc[rr][cc];
}

// tier1: transpose+split comb f32 -> combTH/combTL. grid 2304.
__global__ void split_combT_kernel(const float* __restrict__ comb,
                                   u16* __restrict__ combTH, u16* __restrict__ combTL)
{
    __shared__ float tile[32][33];
    int bid = blockIdx.x, t = threadIdx.x;
    int k = bid / 576, rem = bid % 576, tr = rem / 24, tc = rem % 24;
    const float* src = comb + (long)k * HH;
    long dbase = (long)k * HH;
    int tx = t & 31, ty = t >> 5;
    #pragma unroll
    for (int i = 0; i < 4; ++i)
        tile[tx][ty + i*8] = src[(long)(tr*32 + ty + i*8) * NH + tc*32 + tx];
    __syncthreads();
    #pragma unroll
    for (int i = 0; i < 4; ++i) {
        float v = tile[ty + i*8][tx];
        u16 hv = f2bf(v);
        u16 lv = f2bf(v - bf2f(hv));
        long o = dbase + (long)(tc*32 + ty + i*8) * NH + tr*32 + tx;
        combTH[o] = hv; combTL[o] = lv;
    }
}

// TIER3: TP[k][bs][j] = bf16((text @ comb[k])[bs][j]) for heads [0, NSTORE).
// BK=64; B = combTH only (B-lo dropped: below TP's bf16 storage quantization).
// 32 KB LDS. AM=1: A hi via gld16 from textH. grid (128, 6, NSTORE).
template <int AM>
__global__ __launch_bounds__(256) void tp_gemm_kernel(
    const float* __restrict__ textf, const u16* __restrict__ textH,
    const u16* __restrict__ combTH, const u16* __restrict__ combTL,
    u16* __restrict__ TP)
{
    __shared__ __align__(16) u16 AsH[128 * 64];
    __shared__ __align__(16) u16 BsH[128 * 64];
    const int t = threadIdx.x;
    const int wave = t >> 6, lane = t & 63;
    const int k = blockIdx.z;
    const long m0 = (long)blockIdx.x * 128;   // bs-rows
    const int n0 = blockIdx.y * 128;          // j-cols
    const u16* BH = combTH + (long)k * HH;

    const int r = t >> 3, ch = t & 7;         // 32 rows x 8 chunks per gld16 call
    const int wm = (wave & 1) * 64, wn = (wave >> 1) * 64;
    const int fr = lane & 15, fq = lane >> 4;

    f32x4 acc[4][4];
    #pragma unroll
    for (int i = 0; i < 4; ++i)
        #pragma unroll
        for (int j = 0; j < 4; ++j) acc[i][j] = (f32x4){0.f, 0.f, 0.f, 0.f};

    for (int h0 = 0; h0 < NH; h0 += 64) {
        if (AM) {
            #pragma unroll
            for (int q = 0; q < 4; ++q)
                gld16(textH + (m0 + q*32 + r) * NH + h0 + ch*8, AsH + q*2048 + t*8);
        } else {
            #pragma unroll
            for (int p = 0; p < 8; ++p) {
                int task = p * 256 + t;
                int row = task >> 4, g = task & 15;
                float4 v = *(const float4*)(textf + (m0 + row) * NH + h0 + g*4);
                ushort4 hv;
                hv.x = f2bf(v.x);
                hv.y = f2bf(v.y);
                hv.z = f2bf(v.z);
                hv.w = f2bf(v.w);
                *(ushort4*)(AsH + row * 64 + g*4) = hv;
            }
        }
        #pragma unroll
        for (int q = 0; q < 4; ++q)
            gld16(BH + (long)(n0 + q*32 + r) * NH + h0 + ch*8, BsH + q*2048 + t*8);
        __syncthreads();
        #pragma unroll
        for (int ks = 0; ks < 2; ++ks) {
            bf16x8 afH[4], bfH[4];
            #pragma unroll
            for (int i = 0; i < 4; ++i) {
                afH[i] = *(const bf16x8*)(AsH + (wm + i*16 + fr)*64 + ks*32 + fq*8);
                bfH[i] = *(const bf16x8*)(BsH + (wn + i*16 + fr)*64 + ks*32 + fq*8);
            }
            #pragma unroll
            for (int i = 0; i < 4; ++i)
                #pragma unroll
                for (int j = 0; j < 4; ++j)
                    acc[i][j] = __builtin_amdgcn_mfma_f32_16x16x32_bf16(afH[i], bfH[j], acc[i][j], 0, 0, 0);
        }
        __syncthreads();
    }
    u16* out = TP + ((long)k * NBS + m0) * NH + n0;
    #pragma unroll
    for (int i = 0; i < 4; ++i) {
        #pragma unroll
        for (int rr = 0; rr < 4; ++rr) {
            int m = wm + i*16 + fq*4 + rr;
            #pragma unroll
            for (int j = 0; j < 4; ++j) {
                int n = wn + j*16 + fr;
                out[(long)m * NH + n] = f2bf(acc[i][j][rr]);
            }
        }
    }
}

// All hops: scores[k][b][s] = We_b[k] + sum_j tanh(TP + W_ht)*We for stored
// heads (writes '='). 64 rows/block. grid (8, 32, NSTORE).
__global__ __launch_bounds__(256) void score_pass_kernel(
    const u16* __restrict__ TP, const float* __restrict__ W_ht,
    const float* __restrict__ WeW, const float* __restrict__ Web,
    float* __restrict__ scores)
{
    __shared__ __align__(16) float bias_s[NH];
    __shared__ __align__(16) float we_s[NH];
    const int t = threadIdx.x;
    const int k = blockIdx.z, b = blockIdx.y;
    const int s0 = blockIdx.x * 64;
    for (int i = t; i < NH; i += 256) {
        bias_s[i] = W_ht[((k << 5) + b) * NH + i];
        we_s[i]   = WeW[k * NH + i];
    }
    __syncthreads();
    const int wave = t >> 6, lane = t & 63;
    const u16* tpb = TP + ((long)k * NBS + (b << 9) + s0) * NH;
    const float web = Web[k];
    for (int sr = wave; sr < 64; sr += 4) {
        const u16* row = tpb + (long)sr * NH;
        float part = 0.f;
        #pragma unroll
        for (int p = 0; p < 3; ++p) {
            const int j = p * 256 + lane * 4;   // 8B/lane bf16 loads, coalesced 512B
            ushort4 v = *(const ushort4*)(row + j);
            float4 bb = *(const float4*)(bias_s + j);
            float4 ww = *(const float4*)(we_s + j);
            part += tanh_fast(bf2f(v.x) + bb.x) * ww.x;
            part += tanh_fast(bf2f(v.y) + bb.y) * ww.y;
            part += tanh_fast(bf2f(v.z) + bb.z) * ww.z;
            part += tanh_fast(bf2f(v.w) + bb.w) * ww.w;
        }
        part += __shfl_xor(part, 1);
        part += __shfl_xor(part, 2);
        part += __shfl_xor(part, 4);
        part += __shfl_xor(part, 8);
        part += __shfl_xor(part, 16);
        part += __shfl_xor(part, 32);
        if (lane == 0) scores[(((k << 5) + b) << 9) + s0 + sr] = part + web;
    }
}

// scores = We_b for heads [koff, NK) (ahead of atomicAdd fused path).
__global__ void init_scores_kernel(const float* __restrict__ Web,
                                   float* __restrict__ scores, int koff)
{
    int idx = (koff << 14) + blockIdx.x * 256 + threadIdx.x;
    scores[idx] = Web[idx >> 14];
}

// W_ht[k][b][j] = Wtb + combB + q.Wt  (full dot, no atomics). grid 384.
__global__ __launch_bounds__(256) void wht2_kernel(
    const float* __restrict__ q, const float* __restrict__ WtW,
    const float* __restrict__ combB, const float* __restrict__ Wtb,
    float* __restrict__ W_ht)
{
    int bid = blockIdx.x;                 // 4k x 32b x 3jt
    int k = bid / 96, rem = bid % 96, b = rem / 3, jt = rem % 3;
    int j = jt * 256 + threadIdx.x;
    const float* W = WtW + (long)k * HH + j;
    const float* qb = q + b * NH;
    float acc = 0.f;
    #pragma unroll 8
    for (int h = 0; h < NH; ++h) acc += qb[h] * W[(long)h * NH];
    W_ht[(k*NB + b) * NH + j] = acc + Wtb[k * NH + j] + combB[k * NH + j];
}

// ---------------------------------------------------------------------------
// MFMA split-bf16 fused scores (W_ht includes combB), head-offset koff.
// grid (128, 6, nheads).
// ---------------------------------------------------------------------------
template <int AM>
__global__ __launch_bounds__(256) void fused_scores_mfma(
    const float* __restrict__ textf,
    const u16* __restrict__ textH, const u16* __restrict__ textL,
    const u16* __restrict__ combTH, const u16* __restrict__ combTL,
    const float* __restrict__ W_ht,
    const float* __restrict__ WeW, float* __restrict__ scores, int koff)
{
    __shared__ __align__(16) u16 AsH[128 * 32];
    __shared__ __align__(16) u16 AsL[128 * 32];
    __shared__ __align__(16) u16 BsH[128 * 32];
    __shared__ __align__(16) u16 BsL[128 * 32];
    __shared__ float wht_s[128];
    __shared__ float we_s[128];
    __shared__ float sred[128];
    const int t = threadIdx.x;
    const int wave = t >> 6, lane = t & 63;
    const int k = koff + blockIdx.z;
    const long m0 = (long)blockIdx.x * 128;
    const int n0 = blockIdx.y * 128;
    const int b = (int)(m0 >> 9), srow = (int)(m0 & 511);
    const u16* BH = combTH + (long)k * HH;
    const u16* BL = combTL + (long)k * HH;

    if (t < 128) {
        wht_s[t] = W_ht[((k << 5) + b) * NH + n0 + t];
        we_s[t]  = WeW[k * NH + n0 + t];
        sred[t]  = 0.f;
    }

    const int r = t >> 2, ch = t & 3;
    const int wm = (wave & 1) * 64, wn = (wave >> 1) * 64;
    const int fr = lane & 15, fq = lane >> 4;

    f32x4 acc[4][4];
    #pragma unroll
    for (int i = 0; i < 4; ++i)
        #pragma unroll
        for (int j = 0; j < 4; ++j) acc[i][j] = (f32x4){0.f, 0.f, 0.f, 0.f};

    for (int h0 = 0; h0 < NH; h0 += 32) {
        if (AM) {
            gld16(textH + (m0 + r)      * NH + h0 + ch*8, AsH + t*8);
            gld16(textH + (m0 + 64 + r) * NH + h0 + ch*8, AsH + 2048 + t*8);
            gld16(textL + (m0 + r)      * NH + h0 + ch*8, AsL + t*8);
            gld16(textL + (m0 + 64 + r) * NH + h0 + ch*8, AsL + 2048 + t*8);
        } else {
            #pragma unroll
            for (int p = 0; p < 4; ++p) {
                int task = p * 256 + t;
                int row = task >> 3, g = task & 7;
                float4 v = *(const float4*)(textf + (m0 + row) * NH + h0 + g*4);
                ushort4 hv, lv;
                hv.x = f2bf(v.x); lv.x = f2bf(v.x - bf2f(hv.x));
                hv.y = f2bf(v.y); lv.y = f2bf(v.y - bf2f(hv.y));
                hv.z = f2bf(v.z); lv.z = f2bf(v.z - bf2f(hv.z));
                hv.w = f2bf(v.w); lv.w = f2bf(v.w - bf2f(hv.w));
                *(ushort4*)(AsH + row * 32 + g*4) = hv;
                *(ushort4*)(AsL + row * 32 + g*4) = lv;
            }
        }
        gld16(BH + (long)(n0 + r)      * NH + h0 + ch*8, BsH + t*8);
        gld16(BH + (long)(n0 + 64 + r) * NH + h0 + ch*8, BsH + 2048 + t*8);
        gld16(BL + (long)(n0 + r)      * NH + h0 + ch*8, BsL + t*8);
        gld16(BL + (long)(n0 + 64 + r) * NH + h0 + ch*8, BsL + 2048 + t*8);
        __syncthreads();
        bf16x8 afH[4], afL[4], bfH[4], bfL[4];
        #pragma unroll
        for (int i = 0; i < 4; ++i) {
            afH[i] = *(const bf16x8*)(AsH + (wm + i*16 + fr)*32 + fq*8);
            afL[i] = *(const bf16x8*)(AsL + (wm + i*16 + fr)*32 + fq*8);
            bfH[i] = *(const bf16x8*)(BsH + (wn + i*16 + fr)*32 + fq*8);
            bfL[i] = *(const bf16x8*)(BsL + (wn + i*16 + fr)*32 + fq*8);
        }
        #pragma unroll
        for (int i = 0; i < 4; ++i)
            #pragma unroll
            for (int j = 0; j < 4; ++j) {
                acc[i][j] = __builtin_amdgcn_mfma_f32_16x16x32_bf16(afH[i], bfH[j], acc[i][j], 0, 0, 0);
                acc[i][j] = __builtin_amdgcn_mfma_f32_16x16x32_bf16(afH[i], bfL[j], acc[i][j], 0, 0, 0);
                acc[i][j] = __builtin_amdgcn_mfma_f32_16x16x32_bf16(afL[i], bfH[j], acc[i][j], 0, 0, 0);
            }
        __syncthreads();
    }
    #pragma unroll
    for (int i = 0; i < 4; ++i) {
        #pragma unroll
        for (int rr = 0; rr < 4; ++rr) {
            int m = wm + i*16 + fq*4 + rr;
            float part = 0.f;
            #pragma unroll
            for (int j = 0; j < 4; ++j) {
                int n = wn + j*16 + fr;
                part += tanh_fast(acc[i][j][rr] + wht_s[n]) * we_s[n];
            }
            part += __shfl_xor(part, 1);
            part += __shfl_xor(part, 2);
            part += __shfl_xor(part, 4);
            part += __shfl_xor(part, 8);
            if (fr == 0) atomicAdd(&sred[m], part);
        }
    }
    __syncthreads();
    if (t < 128)
        atomicAdd(&scores[(((k << 5) + b) << 9) + srow + t], sred[t]);
}

// tier0 fallback (W_ht includes combB). grid (256, 6, 4).
__global__ __launch_bounds__(256) void fused_scores_valu(
    const float* __restrict__ text, const float* __restrict__ comb,
    const float* __restrict__ W_ht,
    const float* __restrict__ WeW, float* __restrict__ scores)
{
    __shared__ float AtT[32][68];
    __shared__ float Bt[32][132];
    __shared__ float wht_s[128];
    __shared__ float we_s[128];
    __shared__ float sred[64];
    const int t = threadIdx.x;
    const int row0 = blockIdx.x * 64;
    const int j0 = blockIdx.y * 128, k = blockIdx.z;
    const int b = row0 >> 9, s0 = row0 & 511;
    const float* B = comb + (long)k * HH;
    const int r4 = (t >> 4) * 4, c8 = (t & 15) * 8;
    if (t < 128) {
        wht_s[t] = W_ht[((k << 5) + b) * NH + j0 + t];
        we_s[t]  = WeW[k * NH + j0 + t];
    }
    if (t < 64) sred[t] = 0.f;
    float acc[4][8];
    #pragma unroll
    for (int rr = 0; rr < 4; ++rr)
        #pragma unroll
        for (int cc = 0; cc < 8; ++cc) acc[rr][cc] = 0.f;
    for (int h0 = 0; h0 < NH; h0 += 32) {
        #pragma unroll
        for (int p = 0; p < 8; ++p) {
            int idx = p * 256 + t;
            int r = idx >> 5, hh = idx & 31;
            AtT[hh][r] = text[(long)(row0 + r) * NH + h0 + hh];
        }
        #pragma unroll
        for (int p = 0; p < 16; ++p) {
            int idx = p * 256 + t;
            int hh = idx >> 7, c = idx & 127;
            Bt[hh][c] = B[(long)(h0 + hh) * NH + j0 + c];
        }
        __syncthreads();
        for (int hh = 0; hh < 32; ++hh) {
            float4 av  = *(const float4*)&AtT[hh][r4];
            float4 bv0 = *(const float4*)&Bt[hh][c8];
            float4 bv1 = *(const float4*)&Bt[hh][c8 + 4];
            float a[4] = {av.x, av.y, av.z, av.w};
            float bb[8] = {bv0.x, bv0.y, bv0.z, bv0.w, bv1.x, bv1.y, bv1.z, bv1.w};
            #pragma unroll
            for (int rr = 0; rr < 4; ++rr)
                #pragma unroll
                for (int cc = 0; cc < 8; ++cc) acc[rr][cc] += a[rr] * bb[cc];
        }
        __syncthreads();
    }
    float part[4] = {0.f, 0.f, 0.f, 0.f};
    #pragma unroll
    for (int rr = 0; rr < 4; ++rr)
        #pragma unroll
        for (int cc = 0; cc < 8; ++cc)
            part[rr] += tanh_fast(acc[rr][cc] + wht_s[c8 + cc]) * we_s[c8 + cc];
    #pragma unroll
    for (int rr = 0; rr < 4; ++rr)
        atomicAdd(&sred[r4 + rr], part[rr]);
    __syncthreads();
    if (t < 64)
        atomicAdd(&scores[(((k << 5) + b) << 9) + s0 + t], sred[t]);
}

// Shuffle-based softmax + head-combine + argmax + xT build. grid 32.
__global__ void softmax_kernel(const float* __restrict__ scores,
                               const float* __restrict__ headw_W, const float* __restrict__ headw_b,
                               const float* __restrict__ text,
                               const float* __restrict__ q_f32,
                               float* __restrict__ xT, float* __restrict__ out_prob, int hop)
{
    __shared__ float sc[NK][NS];
    __shared__ float cred[4];
    __shared__ float cval[4];
    __shared__ int   cidx[4];
    int b = blockIdx.x, t = threadIdx.x;
    int wave = t >> 6, lane = t & 63;
    for (int i = t; i < NK * NS; i += 256) {
        int k = i >> 9, s = i & 511;
        sc[k][s] = scores[((k*NB + b) << 9) + s];
    }
    __syncthreads();
    float fac[NK];
    for (int k = 0; k < NK; ++k) {
        float v0 = sc[k][t], v1 = sc[k][t + 256];
        float m = fmaxf(v0, v1);
        #pragma unroll
        for (int o = 32; o > 0; o >>= 1) m = fmaxf(m, __shfl_xor(m, o));
        if (lane == 0) cred[wave] = m;
        __syncthreads();
        float mx = fmaxf(fmaxf(cred[0], cred[1]), fmaxf(cred[2], cred[3]));
        __syncthreads();
        float e0 = __expf(v0 - mx), e1 = __expf(v1 - mx);
        sc[k][t] = e0; sc[k][t + 256] = e1;
        float sm = e0 + e1;
        #pragma unroll
        for (int o = 32; o > 0; o >>= 1) sm += __shfl_xor(sm, o);
        if (lane == 0) cred[wave] = sm;
        __syncthreads();
        fac[k] = headw_W[k] / (cred[0] + cred[1] + cred[2] + cred[3]);
        __syncthreads();
    }
    float hwb = headw_b[0];
    float a0 = hwb, a1 = hwb;
    for (int k = 0; k < NK; ++k) { a0 += sc[k][t] * fac[k]; a1 += sc[k][t + 256] * fac[k]; }
    float ss = a0*a0 + a1*a1;
    #pragma unroll
    for (int o = 32; o > 0; o >>= 1) ss += __shfl_xor(ss, o);
    float bv; int bi;
    if (a0 >= a1) { bv = a0; bi = t; } else { bv = a1; bi = t + 256; }
    #pragma unroll
    for (int o = 1; o < 64; o <<= 1) {
        float ov = __shfl_xor(bv, o);
        int   oi = __shfl_xor(bi, o);
        if (ov > bv || (ov == bv && oi < bi)) { bv = ov; bi = oi; }
    }
    if (lane == 0) { cred[wave] = ss; cval[wave] = bv; cidx[wave] = bi; }
    __syncthreads();
    float scale = sqrtf(cred[0] + cred[1] + cred[2] + cred[3]);
    float mbv = cval[0]; int mbi = cidx[0];
    #pragma unroll
    for (int w = 1; w < 4; ++w)
        if (cval[w] > mbv || (cval[w] == mbv && cidx[w] < mbi)) { mbv = cval[w]; mbi = cidx[w]; }
    int idx = mbi;
    if (hop == 0) {
        out_prob[(b << 9) + t]       = a0 / scale;
        out_prob[(b << 9) + t + 256] = a1 / scale;
    }
    const float* trow = text + (long)(b * NS + idx) * NH;
    for (int i = t; i < NH; i += 256) {
        xT[i * NB + b]        = q_f32[b*NH + i];
        xT[(NH + i) * NB + b] = trow[i];
    }
}

// GRU matvec partials: grid (36 j-tiles, 9 chunks: 6 sx + 3 sh); atomicAdd.
__global__ __launch_bounds__(256) void gru_mm3_kernel(
    const float* __restrict__ Wih, const float* __restrict__ Whh,
    const float* __restrict__ xT, const float* __restrict__ hT,
    float* __restrict__ sx, float* __restrict__ sh)
{
    __shared__ float xs[8192];
    int t = threadIdx.x;
    int tj = t & 63, tq = t >> 6;
    int j = blockIdx.x * 64 + tj;
    int cgi = blockIdx.y;
    const float* W; const float* src; float* dst; int c;
    if (cgi < 6) { W = Wih; src = xT; dst = sx; c = cgi; }
    else         { W = Whh; src = hT; dst = sh; c = cgi - 6; }
    for (int idx = t; idx < 8192; idx += 256) xs[idx] = src[c * 8192 + idx];
    __syncthreads();
    float acc[8];
    #pragma unroll
    for (int bq = 0; bq < 8; ++bq) acc[bq] = 0.f;
    #pragma unroll 8
    for (int ii = 0; ii < 256; ++ii) {
        float w = W[(long)(c * 256 + ii) * H3 + j];
        #pragma unroll
        for (int bq = 0; bq < 8; ++bq) acc[bq] += xs[ii * 32 + tq * 8 + bq] * w;
    }
    #pragma unroll
    for (int bq = 0; bq < 8; ++bq)
        atomicAdd(&dst[(long)(tq * 8 + bq) * H3 + j], acc[bq]);
}

// Gate + h/q update; re-zeroes sx/sh for the next hop after reading.
__global__ void gate_kernel(const float* __restrict__ bih, const float* __restrict__ bhh,
                            float* __restrict__ sx, float* __restrict__ sh,
                            float* __restrict__ hT, float* __restrict__ q_f32,
                            float* __restrict__ out_h, int hop)
{
    int gid = blockIdx.x * 256 + threadIdx.x;
    int b = gid / NH, j = gid % NH;
    float xr = bih[j]        + sx[b*H3 + j];
    float xz = bih[NH + j]   + sx[b*H3 + NH + j];
    float xn = bih[1536 + j] + sx[b*H3 + 1536 + j];
    float hr = bhh[j]        + sh[b*H3 + j];
    float hz = bhh[NH + j]   + sh[b*H3 + NH + j];
    float hn = bhh[1536 + j] + sh[b*H3 + 1536 + j];
    sx[b*H3 + j] = 0.f; sx[b*H3 + NH + j] = 0.f; sx[b*H3 + 1536 + j] = 0.f;
    sh[b*H3 + j] = 0.f; sh[b*H3 + NH + j] = 0.f; sh[b*H3 + 1536 + j] = 0.f;
    float r = sig_fast(xr + hr);
    float z = sig_fast(xz + hz);
    float n = tanh_fast(xn + r * hn);
    float hp = hT[j * NB + b];
    float hnew = (1.f - z) * n + z * hp;
    hT[j * NB + b] = hnew;
    q_f32[gid] = hnew;
    out_h[(long)(b * 3 + hop) * NH + j] = hnew;
}

// ---------------------------------------------------------------------------
extern "C" void kernel_launch(void* const* d_in, const int* in_sizes, int n_in,
                              void* d_out, int out_size, void* d_ws, size_t ws_size,
                              hipStream_t stream)
{
    const float* question = (const float*)d_in[0];
    const float* text     = (const float*)d_in[1];
    const float* pw_W     = (const float*)d_in[2];
    const float* pw_b     = (const float*)d_in[3];
    const float* Ws_W     = (const float*)d_in[4];
    const float* Ws_b     = (const float*)d_in[5];
    const float* Wt_W     = (const float*)d_in[6];
    const float* Wt_b     = (const float*)d_in[7];
    const float* We_W     = (const float*)d_in[8];
    const float* We_b     = (const float*)d_in[9];
    const float* headw_W  = (const float*)d_in[10];
    const float* headw_b  = (const float*)d_in[11];
    const float* Wih      = (const float*)d_in[12];
    const float* Whh      = (const float*)d_in[13];
    const float* bih      = (const float*)d_in[14];
    const float* bhh      = (const float*)d_in[15];

    char* ws = (char*)d_ws;
    float* comb   = (float*)(ws + 0);
    float* combB  = (float*)(ws + 9437184);
    float* W_ht   = (float*)(ws + 9449472);
    float* scores = (float*)(ws + 9842688);
    float* q_f32  = (float*)(ws + 10104832);
    float* hT     = (float*)(ws + 10203136);
    float* xT     = (float*)(ws + 10301440);
    float* sx     = (float*)(ws + 10498048);
    float* sh     = (float*)(ws + 10792960);
    u16*   combTH = (u16*)  (ws + 11087872);
    u16*   combTL = (u16*)  (ws + 15806464);
    u16*   TP     = (u16*)  (ws + 20525056);
    u16*   textH  = (u16*)  (ws + 121188352);
    // prep scratch overlaid on TP region (dead before tp_gemm runs):
    u16*   WsTH   = (u16*)  (ws + 20525056);
    u16*   WsTL   = (u16*)  (ws + 25243648);
    u16*   pwH    = (u16*)  (ws + 29962240);
    u16*   pwL    = (u16*)  (ws + 34680832);

    int nstore = 0;
    if (ws_size >= (size_t)70856704) {
        long avail = (long)ws_size - 20525056L;
        nstore = (int)(avail / 25165824L);
        if (nstore > NK) nstore = NK;
    }
    const int tier = (nstore >= 1) ? 3
                   : (ws_size >= (size_t)20525056) ? 1 : 0;
    const bool haveTextH = (tier == 3) && (nstore == NK)
                        && (ws_size >= (size_t)146354176);

    float* out_prob = (float*)d_out;
    float* out_h    = (float*)d_out + NB * NS;

    const int prepGrid = haveTextH ? 17968 : (tier >= 2 ? 5680 : 1072);
    prep_kernel<<<prepGrid, 256, 0, stream>>>(
        Ws_W, pw_b, Ws_b, combB, question, q_f32, hT, sx, sh, We_b, scores,
        pw_W, WsTH, WsTL, pwH, pwL, text, textH,
        tier >= 3 ? 2 : tier, haveTextH ? 1 : 0);

    if (tier == 3) {
        comb_mfma_kernel<<<dim3(6, 6, 4), 256, 0, stream>>>(WsTH, WsTL, pwH, pwL,
                                                            combTH, combTL);
        // scratch dead from here; TP overwrites it.
        if (haveTextH) {
            tp_gemm_kernel<1><<<dim3(128, 6, nstore), 256, 0, stream>>>(
                text, textH, combTH, combTL, TP);
        } else {
            tp_gemm_kernel<0><<<dim3(128, 6, nstore), 256, 0, stream>>>(
                text, nullptr, combTH, combTL, TP);
        }
    } else {
        comb_valu_kernel<<<dim3(12, 6, 4), 256, 0, stream>>>(pw_W, Ws_W, comb);
        if (tier == 1)
            split_combT_kernel<<<2304, 256, 0, stream>>>(comb, combTH, combTL);
    }

    for (int hop = 0; hop < 3; ++hop) {
        wht2_kernel<<<384, 256, 0, stream>>>(q_f32, Wt_W, combB, Wt_b, W_ht);
        if (tier == 3) {
            score_pass_kernel<<<dim3(8, 32, nstore), 256, 0, stream>>>(
                TP, W_ht, We_W, We_b, scores);
            if (nstore < NK) {
                if (hop > 0)
                    init_scores_kernel<<<(NK - nstore) * 64, 256, 0, stream>>>(
                        We_b, scores, nstore);
                fused_scores_mfma<0><<<dim3(128, 6, NK - nstore), 256, 0, stream>>>(
                    text, nullptr, nullptr, combTH, combTL, W_ht, We_W,
                    scores, nstore);
            }
        } else if (tier == 1) {
            init_scores_kernel<<<256, 256, 0, stream>>>(We_b, scores, 0);
            fused_scores_mfma<0><<<dim3(128, 6, 4), 256, 0, stream>>>(
                text, nullptr, nullptr, combTH, combTL, W_ht, We_W, scores, 0);
        } else {
            init_scores_kernel<<<256, 256, 0, stream>>>(We_b, scores, 0);
            fused_scores_valu<<<dim3(256, 6, 4), 256, 0, stream>>>(
                text, comb, W_ht, We_W, scores);
        }
        softmax_kernel<<<32, 256, 0, stream>>>(scores, headw_W, headw_b, text,
                                               q_f32, xT, out_prob, hop);
        gru_mm3_kernel<<<dim3(36, 9), 256, 0, stream>>>(Wih, Whh, xT, hT, sx, sh);
        gate_kernel<<<96, 256, 0, stream>>>(bih, bhh, sx, sh, hT, q_f32, out_h, hop);
    }
}

// Round 14
// 556.796 us; speedup vs baseline: 4.3908x; 1.0372x over previous
//
#include <hip/hip_runtime.h>

typedef unsigned short u16;
typedef __bf16 bf16x8 __attribute__((ext_vector_type(8)));
typedef float f32x4 __attribute__((ext_vector_type(4)));

#define NB 32          // batch
#define NS 512         // seq
#define NH 768         // hidden
#define NK 4           // heads
#define NBS 16384      // B*S
#define H3 2304        // 3H
#define HH 589824      // 768*768

__device__ inline float bf2f(u16 u) {
    unsigned x = ((unsigned)u) << 16;
    return __builtin_bit_cast(float, x);
}
__device__ inline u16 f2bf(float f) {
    unsigned u = __builtin_bit_cast(unsigned, f);
    u += 0x7fffu + ((u >> 16) & 1u);
    return (u16)(u >> 16);
}
// fast tanh: 1 - 2*rcp(exp(2x)+1). ~5 VALU vs ~20+ for libm tanhf. err ~1e-6.
__device__ inline float tanh_fast(float x) {
    float e = __expf(2.f * x);
    return 1.f - 2.f * __builtin_amdgcn_rcpf(e + 1.f);
}
__device__ inline float sig_fast(float x) {
    return __builtin_amdgcn_rcpf(1.f + __expf(-x));
}
// async global->LDS, 16B/lane; LDS dst = wave-uniform base + lane*16 (m97 recipe).
__device__ inline void gld16(const u16* g, u16* l) {
    __builtin_amdgcn_global_load_lds(
        (const __attribute__((address_space(1))) unsigned int*)g,
        (__attribute__((address_space(3))) unsigned int*)l, 16, 0, 0);
}

// ---------------------------------------------------------------------------
// Workspace layout (bytes): unchanged from R9/R12/R13.
//  comb @ 0 | combB @ 9,437,184 | W_ht @ 9,449,472 | scores @ 9,842,688
//  q_f32 @ 10,104,832 | hT @ 10,203,136 | xT @ 10,301,440
//  sx @ 10,498,048 | sh @ 10,792,960 | combTH @ 11,087,872 | combTL @ 15,806,464
//  TP @ 20,525,056 (NSTORE x 25,165,824 bf16) | textH @ 121,188,352
//  prep scratch overlaid on TP: WsTH/WsTL/pwH/pwL (WsTL/pwL now unused).
//
// R14: extend R13's argument upstream. comb is consumed only through combTH
// (bf16) in tier 3, so comb_mfma's split-precision correction MFMAs (H*Lo,
// Lo*H) are below combTH's own storage quantization — drop them (1 MFMA,
// half staging, LDS 32->16 KB) and stop producing WsTL/pwL in prep
// (~14 MB fewer writes). R13 measured absmax unchanged for the same class
// of change. Everything else byte-identical to R13 (577 us proven:
// tp_gemm 110 us, hop chain ~130 us/hop).
// ---------------------------------------------------------------------------

// P: one-time prep. grid up to 17968 (sections gated).
__global__ void prep_kernel(const float* __restrict__ WsW, const float* __restrict__ pwb,
                            const float* __restrict__ Wsb, float* __restrict__ combB,
                            const float* __restrict__ question,
                            float* __restrict__ q_f32, float* __restrict__ hT,
                            float* __restrict__ sx, float* __restrict__ sh,
                            const float* __restrict__ Web, float* __restrict__ scores,
                            const float* __restrict__ pwW,
                            u16* __restrict__ WsTH, u16* __restrict__ pwH,
                            const float* __restrict__ text, u16* __restrict__ textH,
                            int tier, int splitText)
{
    int bid = blockIdx.x, t = threadIdx.x;
    if (bid < 48) {
        int idx = bid * 64 + (t >> 2);      // 0..3071
        int ph = t & 3;
        int k = idx / NH, j = idx % NH;
        const float* W = WsW + (long)k * HH + j;
        const float* pb = pwb + k * NH;
        float acc = 0.f;
        #pragma unroll 8
        for (int m = ph * 192; m < ph * 192 + 192; ++m)
            acc += pb[m] * W[(long)m * NH];
        acc += __shfl_xor(acc, 1);
        acc += __shfl_xor(acc, 2);
        if (ph == 0) combB[idx] = acc + Wsb[idx];
    } else if (bid < 144) {
        int idx = (bid - 48) * 256 + t;
        q_f32[idx] = question[idx];
    } else if (bid < 240) {
        int idx = (bid - 144) * 256 + t;
        hT[idx] = 0.f;
    } else if (bid < 816) {
        int idx = (bid - 240) * 256 + t;    // 147,456 floats
        if (idx < 73728) sx[idx] = 0.f;
        else sh[idx - 73728] = 0.f;
    } else if (bid < 1072) {
        int idx = (bid - 816) * 256 + t;    // 65,536: scores = We_b (hop 0,
        scores[idx] = Web[idx >> 14];       // needed for fused leftover heads)
    } else if (bid < 3376) {
        if (tier < 2) return;
        __shared__ float tile[32][33];
        int bid2 = bid - 1072;
        int k = bid2 / 576, rem = bid2 % 576, tr = rem / 24, tc = rem % 24;
        const float* src = WsW + (long)k * HH;
        long dbase = (long)k * HH;
        int tx = t & 31, ty = t >> 5;
        #pragma unroll
        for (int i = 0; i < 4; ++i)
            tile[tx][ty + i*8] = src[(long)(tr*32 + ty + i*8) * NH + tc*32 + tx];
        __syncthreads();
        #pragma unroll
        for (int i = 0; i < 4; ++i) {
            float v = tile[ty + i*8][tx];
            long o = dbase + (long)(tc*32 + ty + i*8) * NH + tr*32 + tx;
            WsTH[o] = f2bf(v);
        }
    } else if (bid < 5680) {
        if (tier < 2) return;
        long base = (long)(bid - 3376) * 1024 + t * 4;
        float4 v = *(const float4*)(pwW + base);
        ushort4 hv;
        hv.x = f2bf(v.x);
        hv.y = f2bf(v.y);
        hv.z = f2bf(v.z);
        hv.w = f2bf(v.w);
        *(ushort4*)(pwH + base) = hv;
    } else {
        if (!splitText) return;
        long base = (long)(bid - 5680) * 1024 + t * 4;
        float4 v = *(const float4*)(text + base);
        ushort4 hv;
        hv.x = f2bf(v.x);
        hv.y = f2bf(v.y);
        hv.z = f2bf(v.z);
        hv.w = f2bf(v.w);
        *(ushort4*)(textH + base) = hv;
    }
}

// combT[k][j][h] = sum_m WsT[k][j][m] * pw[k][h][m], bf16 1-MFMA (lo terms
// dropped: below combTH's bf16 storage quantization — R13 argument).
// combTL still written (residual of the computed value; used by fallbacks).
__global__ __launch_bounds__(256) void comb_mfma_kernel(
    const u16* __restrict__ WsTH, const u16* __restrict__ pwH,
    u16* __restrict__ combTH, u16* __restrict__ combTL)
{
    __shared__ __align__(16) u16 AsH[128 * 32];
    __shared__ __align__(16) u16 BsH[128 * 32];
    const int t = threadIdx.x;
    const int wave = t >> 6, lane = t & 63;
    const int k = blockIdx.z;
    const long m0 = (long)blockIdx.x * 128;   // j-rows
    const int n0 = blockIdx.y * 128;          // h-cols
    const u16* AH = WsTH + (long)k * HH;
    const u16* BH = pwH + (long)k * HH;

    const int r = t >> 2, ch = t & 3;
    const int wm = (wave & 1) * 64, wn = (wave >> 1) * 64;
    const int fr = lane & 15, fq = lane >> 4;

    f32x4 acc[4][4];
    #pragma unroll
    for (int i = 0; i < 4; ++i)
        #pragma unroll
        for (int j = 0; j < 4; ++j) acc[i][j] = (f32x4){0.f, 0.f, 0.f, 0.f};

    for (int k0 = 0; k0 < NH; k0 += 32) {
        gld16(AH + (m0 + r)      * NH + k0 + ch*8, AsH + t*8);
        gld16(AH + (m0 + 64 + r) * NH + k0 + ch*8, AsH + 2048 + t*8);
        gld16(BH + (long)(n0 + r)      * NH + k0 + ch*8, BsH + t*8);
        gld16(BH + (long)(n0 + 64 + r) * NH + k0 + ch*8, BsH + 2048 + t*8);
        __syncthreads();
        bf16x8 afH[4], bfH[4];
        #pragma unroll
        for (int i = 0; i < 4; ++i) {
            afH[i] = *(const bf16x8*)(AsH + (wm + i*16 + fr)*32 + fq*8);
            bfH[i] = *(const bf16x8*)(BsH + (wn + i*16 + fr)*32 + fq*8);
        }
        #pragma unroll
        for (int i = 0; i < 4; ++i)
            #pragma unroll
            for (int j = 0; j < 4; ++j)
                acc[i][j] = __builtin_amdgcn_mfma_f32_16x16x32_bf16(afH[i], bfH[j], acc[i][j], 0, 0, 0);
        __syncthreads();
    }
    long kb = (long)k * HH;
    #pragma unroll
    for (int i = 0; i < 4; ++i) {
        long m = m0 + wm + i*16 + fq*4;       // j-row
        #pragma unroll
        for (int j = 0; j < 4; ++j) {
            long n = n0 + wn + j*16 + fr;     // h-col
            #pragma unroll
            for (int rr = 0; rr < 4; ++rr) {
                float v = acc[i][j][rr];
                u16 hv = f2bf(v);
                u16 lv = f2bf(v - bf2f(hv));
                combTH[kb + (m + rr) * NH + n] = hv;
                combTL[kb + (m + rr) * NH + n] = lv;
            }
        }
    }
}

// tier 0/1: comb[k][h][j] f32 VALU GEMM (proven R8 kernel).
__global__ __launch_bounds__(256) void comb_valu_kernel(
    const float* __restrict__ pwW, const float* __restrict__ WsW,
    float* __restrict__ comb)
{
    __shared__ float AtT[32][68];
    __shared__ float Bt[32][132];
    const int t = threadIdx.x;
    const int m0 = blockIdx.x * 64, j0 = blockIdx.y * 128, k = blockIdx.z;
    const float* A = pwW + (long)k * HH;
    const float* B = WsW + (long)k * HH;
    const int r4 = (t >> 4) * 4, c8 = (t & 15) * 8;
    float acc[4][8];
    #pragma unroll
    for (int rr = 0; rr < 4; ++rr)
        #pragma unroll
        for (int cc = 0; cc < 8; ++cc) acc[rr][cc] = 0.f;
    for (int h0 = 0; h0 < NH; h0 += 32) {
        #pragma unroll
        for (int p = 0; p < 8; ++p) {
            int idx = p * 256 + t;
            int r = idx >> 5, hh = idx & 31;
            AtT[hh][r] = A[(long)(m0 + r) * NH + h0 + hh];
        }
        #pragma unroll
        for (int p = 0; p < 16; ++p) {
            int idx = p * 256 + t;
            int hh = idx >> 7, c = idx & 127;
            Bt[hh][c] = B[(long)(h0 + hh) * NH + j0 + c];
        }
        __syncthreads();
        for (int hh = 0; hh < 32; ++hh) {
            float4 av  = *(const float4*)&AtT[hh][r4];
            float4 bv0 = *(const float4*)&Bt[hh][c8];
            float4 bv1 = *(const float4*)&Bt[hh][c8 + 4];
            float a[4] = {av.x, av.y, av.z, av.w};
            float bb[8] = {bv0.x, bv0.y, bv0.z, bv0.w, bv1.x, bv1.y, bv1.z, bv1.w};
            #pragma unroll
            for (int rr = 0; rr < 4; ++rr)
                #pragma unroll
                for (int cc = 0; cc < 8; ++cc) acc[rr][cc] += a[rr] * bb[cc];
        }
        __syncthreads();
    }
    float* C = comb + (long)k * HH;
    #pragma unroll
    for (int rr = 0; rr < 4; ++rr)
        #pragma unroll
        for (int cc = 0; cc < 8; ++cc)
            C[(long)(m0 + r4 + rr) * NH + j0 + c8 + cc] = acc[rr][cc];
}

// tier1: transpose+split comb f32 -> combTH/combTL. grid 2304.
__global__ void split_combT_kernel(const float* __restrict__ comb,
                                   u16* __restrict__ combTH, u16* __restrict__ combTL)
{
    __shared__ float tile[32][33];
    int bid = blockIdx.x, t = threadIdx.x;
    int k = bid / 576, rem = bid % 576, tr = rem / 24, tc = rem % 24;
    const float* src = comb + (long)k * HH;
    long dbase = (long)k * HH;
    int tx = t & 31, ty = t >> 5;
    #pragma unroll
    for (int i = 0; i < 4; ++i)
        tile[tx][ty + i*8] = src[(long)(tr*32 + ty + i*8) * NH + tc*32 + tx];
    __syncthreads();
    #pragma unroll
    for (int i = 0; i < 4; ++i) {
        float v = tile[ty + i*8][tx];
        u16 hv = f2bf(v);
        u16 lv = f2bf(v - bf2f(hv));
        long o = dbase + (long)(tc*32 + ty + i*8) * NH + tr*32 + tx;
        combTH[o] = hv; combTL[o] = lv;
    }
}

// TIER3: TP[k][bs][j] = bf16((text @ comb[k])[bs][j]) for heads [0, NSTORE).
// BK=64; B = combTH only (B-lo dropped: below TP's bf16 storage quantization).
// 32 KB LDS. AM=1: A hi via gld16 from textH. grid (128, 6, NSTORE).
template <int AM>
__global__ __launch_bounds__(256) void tp_gemm_kernel(
    const float* __restrict__ textf, const u16* __restrict__ textH,
    const u16* __restrict__ combTH, const u16* __restrict__ combTL,
    u16* __restrict__ TP)
{
    __shared__ __align__(16) u16 AsH[128 * 64];
    __shared__ __align__(16) u16 BsH[128 * 64];
    const int t = threadIdx.x;
    const int wave = t >> 6, lane = t & 63;
    const int k = blockIdx.z;
    const long m0 = (long)blockIdx.x * 128;   // bs-rows
    const int n0 = blockIdx.y * 128;          // j-cols
    const u16* BH = combTH + (long)k * HH;

    const int r = t >> 3, ch = t & 7;         // 32 rows x 8 chunks per gld16 call
    const int wm = (wave & 1) * 64, wn = (wave >> 1) * 64;
    const int fr = lane & 15, fq = lane >> 4;

    f32x4 acc[4][4];
    #pragma unroll
    for (int i = 0; i < 4; ++i)
        #pragma unroll
        for (int j = 0; j < 4; ++j) acc[i][j] = (f32x4){0.f, 0.f, 0.f, 0.f};

    for (int h0 = 0; h0 < NH; h0 += 64) {
        if (AM) {
            #pragma unroll
            for (int q = 0; q < 4; ++q)
                gld16(textH + (m0 + q*32 + r) * NH + h0 + ch*8, AsH + q*2048 + t*8);
        } else {
            #pragma unroll
            for (int p = 0; p < 8; ++p) {
                int task = p * 256 + t;
                int row = task >> 4, g = task & 15;
                float4 v = *(const float4*)(textf + (m0 + row) * NH + h0 + g*4);
                ushort4 hv;
                hv.x = f2bf(v.x);
                hv.y = f2bf(v.y);
                hv.z = f2bf(v.z);
                hv.w = f2bf(v.w);
                *(ushort4*)(AsH + row * 64 + g*4) = hv;
            }
        }
        #pragma unroll
        for (int q = 0; q < 4; ++q)
            gld16(BH + (long)(n0 + q*32 + r) * NH + h0 + ch*8, BsH + q*2048 + t*8);
        __syncthreads();
        #pragma unroll
        for (int ks = 0; ks < 2; ++ks) {
            bf16x8 afH[4], bfH[4];
            #pragma unroll
            for (int i = 0; i < 4; ++i) {
                afH[i] = *(const bf16x8*)(AsH + (wm + i*16 + fr)*64 + ks*32 + fq*8);
                bfH[i] = *(const bf16x8*)(BsH + (wn + i*16 + fr)*64 + ks*32 + fq*8);
            }
            #pragma unroll
            for (int i = 0; i < 4; ++i)
                #pragma unroll
                for (int j = 0; j < 4; ++j)
                    acc[i][j] = __builtin_amdgcn_mfma_f32_16x16x32_bf16(afH[i], bfH[j], acc[i][j], 0, 0, 0);
        }
        __syncthreads();
    }
    u16* out = TP + ((long)k * NBS + m0) * NH + n0;
    #pragma unroll
    for (int i = 0; i < 4; ++i) {
        #pragma unroll
        for (int rr = 0; rr < 4; ++rr) {
            int m = wm + i*16 + fq*4 + rr;
            #pragma unroll
            for (int j = 0; j < 4; ++j) {
                int n = wn + j*16 + fr;
                out[(long)m * NH + n] = f2bf(acc[i][j][rr]);
            }
        }
    }
}

// All hops: scores[k][b][s] = We_b[k] + sum_j tanh(TP + W_ht)*We for stored
// heads (writes '='). 64 rows/block. grid (8, 32, NSTORE).
__global__ __launch_bounds__(256) void score_pass_kernel(
    const u16* __restrict__ TP, const float* __restrict__ W_ht,
    const float* __restrict__ WeW, const float* __restrict__ Web,
    float* __restrict__ scores)
{
    __shared__ __align__(16) float bias_s[NH];
    __shared__ __align__(16) float we_s[NH];
    const int t = threadIdx.x;
    const int k = blockIdx.z, b = blockIdx.y;
    const int s0 = blockIdx.x * 64;
    for (int i = t; i < NH; i += 256) {
        bias_s[i] = W_ht[((k << 5) + b) * NH + i];
        we_s[i]   = WeW[k * NH + i];
    }
    __syncthreads();
    const int wave = t >> 6, lane = t & 63;
    const u16* tpb = TP + ((long)k * NBS + (b << 9) + s0) * NH;
    const float web = Web[k];
    for (int sr = wave; sr < 64; sr += 4) {
        const u16* row = tpb + (long)sr * NH;
        float part = 0.f;
        #pragma unroll
        for (int p = 0; p < 3; ++p) {
            const int j = p * 256 + lane * 4;   // 8B/lane bf16 loads, coalesced 512B
            ushort4 v = *(const ushort4*)(row + j);
            float4 bb = *(const float4*)(bias_s + j);
            float4 ww = *(const float4*)(we_s + j);
            part += tanh_fast(bf2f(v.x) + bb.x) * ww.x;
            part += tanh_fast(bf2f(v.y) + bb.y) * ww.y;
            part += tanh_fast(bf2f(v.z) + bb.z) * ww.z;
            part += tanh_fast(bf2f(v.w) + bb.w) * ww.w;
        }
        part += __shfl_xor(part, 1);
        part += __shfl_xor(part, 2);
        part += __shfl_xor(part, 4);
        part += __shfl_xor(part, 8);
        part += __shfl_xor(part, 16);
        part += __shfl_xor(part, 32);
        if (lane == 0) scores[(((k << 5) + b) << 9) + s0 + sr] = part + web;
    }
}

// scores = We_b for heads [koff, NK) (ahead of atomicAdd fused path).
__global__ void init_scores_kernel(const float* __restrict__ Web,
                                   float* __restrict__ scores, int koff)
{
    int idx = (koff << 14) + blockIdx.x * 256 + threadIdx.x;
    scores[idx] = Web[idx >> 14];
}

// W_ht[k][b][j] = Wtb + combB + q.Wt  (full dot, no atomics). grid 384.
__global__ __launch_bounds__(256) void wht2_kernel(
    const float* __restrict__ q, const float* __restrict__ WtW,
    const float* __restrict__ combB, const float* __restrict__ Wtb,
    float* __restrict__ W_ht)
{
    int bid = blockIdx.x;                 // 4k x 32b x 3jt
    int k = bid / 96, rem = bid % 96, b = rem / 3, jt = rem % 3;
    int j = jt * 256 + threadIdx.x;
    const float* W = WtW + (long)k * HH + j;
    const float* qb = q + b * NH;
    float acc = 0.f;
    #pragma unroll 8
    for (int h = 0; h < NH; ++h) acc += qb[h] * W[(long)h * NH];
    W_ht[(k*NB + b) * NH + j] = acc + Wtb[k * NH + j] + combB[k * NH + j];
}

// ---------------------------------------------------------------------------
// MFMA split-bf16 fused scores (W_ht includes combB), head-offset koff.
// grid (128, 6, nheads).
// ---------------------------------------------------------------------------
template <int AM>
__global__ __launch_bounds__(256) void fused_scores_mfma(
    const float* __restrict__ textf,
    const u16* __restrict__ textH, const u16* __restrict__ textL,
    const u16* __restrict__ combTH, const u16* __restrict__ combTL,
    const float* __restrict__ W_ht,
    const float* __restrict__ WeW, float* __restrict__ scores, int koff)
{
    __shared__ __align__(16) u16 AsH[128 * 32];
    __shared__ __align__(16) u16 AsL[128 * 32];
    __shared__ __align__(16) u16 BsH[128 * 32];
    __shared__ __align__(16) u16 BsL[128 * 32];
    __shared__ float wht_s[128];
    __shared__ float we_s[128];
    __shared__ float sred[128];
    const int t = threadIdx.x;
    const int wave = t >> 6, lane = t & 63;
    const int k = koff + blockIdx.z;
    const long m0 = (long)blockIdx.x * 128;
    const int n0 = blockIdx.y * 128;
    const int b = (int)(m0 >> 9), srow = (int)(m0 & 511);
    const u16* BH = combTH + (long)k * HH;
    const u16* BL = combTL + (long)k * HH;

    if (t < 128) {
        wht_s[t] = W_ht[((k << 5) + b) * NH + n0 + t];
        we_s[t]  = WeW[k * NH + n0 + t];
        sred[t]  = 0.f;
    }

    const int r = t >> 2, ch = t & 3;
    const int wm = (wave & 1) * 64, wn = (wave >> 1) * 64;
    const int fr = lane & 15, fq = lane >> 4;

    f32x4 acc[4][4];
    #pragma unroll
    for (int i = 0; i < 4; ++i)
        #pragma unroll
        for (int j = 0; j < 4; ++j) acc[i][j] = (f32x4){0.f, 0.f, 0.f, 0.f};

    for (int h0 = 0; h0 < NH; h0 += 32) {
        if (AM) {
            gld16(textH + (m0 + r)      * NH + h0 + ch*8, AsH + t*8);
            gld16(textH + (m0 + 64 + r) * NH + h0 + ch*8, AsH + 2048 + t*8);
            gld16(textL + (m0 + r)      * NH + h0 + ch*8, AsL + t*8);
            gld16(textL + (m0 + 64 + r) * NH + h0 + ch*8, AsL + 2048 + t*8);
        } else {
            #pragma unroll
            for (int p = 0; p < 4; ++p) {
                int task = p * 256 + t;
                int row = task >> 3, g = task & 7;
                float4 v = *(const float4*)(textf + (m0 + row) * NH + h0 + g*4);
                ushort4 hv, lv;
                hv.x = f2bf(v.x); lv.x = f2bf(v.x - bf2f(hv.x));
                hv.y = f2bf(v.y); lv.y = f2bf(v.y - bf2f(hv.y));
                hv.z = f2bf(v.z); lv.z = f2bf(v.z - bf2f(hv.z));
                hv.w = f2bf(v.w); lv.w = f2bf(v.w - bf2f(hv.w));
                *(ushort4*)(AsH + row * 32 + g*4) = hv;
                *(ushort4*)(AsL + row * 32 + g*4) = lv;
            }
        }
        gld16(BH + (long)(n0 + r)      * NH + h0 + ch*8, BsH + t*8);
        gld16(BH + (long)(n0 + 64 + r) * NH + h0 + ch*8, BsH + 2048 + t*8);
        gld16(BL + (long)(n0 + r)      * NH + h0 + ch*8, BsL + t*8);
        gld16(BL + (long)(n0 + 64 + r) * NH + h0 + ch*8, BsL + 2048 + t*8);
        __syncthreads();
        bf16x8 afH[4], afL[4], bfH[4], bfL[4];
        #pragma unroll
        for (int i = 0; i < 4; ++i) {
            afH[i] = *(const bf16x8*)(AsH + (wm + i*16 + fr)*32 + fq*8);
            afL[i] = *(const bf16x8*)(AsL + (wm + i*16 + fr)*32 + fq*8);
            bfH[i] = *(const bf16x8*)(BsH + (wn + i*16 + fr)*32 + fq*8);
            bfL[i] = *(const bf16x8*)(BsL + (wn + i*16 + fr)*32 + fq*8);
        }
        #pragma unroll
        for (int i = 0; i < 4; ++i)
            #pragma unroll
            for (int j = 0; j < 4; ++j) {
                acc[i][j] = __builtin_amdgcn_mfma_f32_16x16x32_bf16(afH[i], bfH[j], acc[i][j], 0, 0, 0);
                acc[i][j] = __builtin_amdgcn_mfma_f32_16x16x32_bf16(afH[i], bfL[j], acc[i][j], 0, 0, 0);
                acc[i][j] = __builtin_amdgcn_mfma_f32_16x16x32_bf16(afL[i], bfH[j], acc[i][j], 0, 0, 0);
            }
        __syncthreads();
    }
    #pragma unroll
    for (int i = 0; i < 4; ++i) {
        #pragma unroll
        for (int rr = 0; rr < 4; ++rr) {
            int m = wm + i*16 + fq*4 + rr;
            float part = 0.f;
            #pragma unroll
            for (int j = 0; j < 4; ++j) {
                int n = wn + j*16 + fr;
                part += tanh_fast(acc[i][j][rr] + wht_s[n]) * we_s[n];
            }
            part += __shfl_xor(part, 1);
            part += __shfl_xor(part, 2);
            part += __shfl_xor(part, 4);
            part += __shfl_xor(part, 8);
            if (fr == 0) atomicAdd(&sred[m], part);
        }
    }
    __syncthreads();
    if (t < 128)
        atomicAdd(&scores[(((k << 5) + b) << 9) + srow + t], sred[t]);
}

// tier0 fallback (W_ht includes combB). grid (256, 6, 4).
__global__ __launch_bounds__(256) void fused_scores_valu(
    const float* __restrict__ text, const float* __restrict__ comb,
    const float* __restrict__ W_ht,
    const float* __restrict__ WeW, float* __restrict__ scores)
{
    __shared__ float AtT[32][68];
    __shared__ float Bt[32][132];
    __shared__ float wht_s[128];
    __shared__ float we_s[128];
    __shared__ float sred[64];
    const int t = threadIdx.x;
    const int row0 = blockIdx.x * 64;
    const int j0 = blockIdx.y * 128, k = blockIdx.z;
    const int b = row0 >> 9, s0 = row0 & 511;
    const float* B = comb + (long)k * HH;
    const int r4 = (t >> 4) * 4, c8 = (t & 15) * 8;
    if (t < 128) {
        wht_s[t] = W_ht[((k << 5) + b) * NH + j0 + t];
        we_s[t]  = WeW[k * NH + j0 + t];
    }
    if (t < 64) sred[t] = 0.f;
    float acc[4][8];
    #pragma unroll
    for (int rr = 0; rr < 4; ++rr)
        #pragma unroll
        for (int cc = 0; cc < 8; ++cc) acc[rr][cc] = 0.f;
    for (int h0 = 0; h0 < NH; h0 += 32) {
        #pragma unroll
        for (int p = 0; p < 8; ++p) {
            int idx = p * 256 + t;
            int r = idx >> 5, hh = idx & 31;
            AtT[hh][r] = text[(long)(row0 + r) * NH + h0 + hh];
        }
        #pragma unroll
        for (int p = 0; p < 16; ++p) {
            int idx = p * 256 + t;
            int hh = idx >> 7, c = idx & 127;
            Bt[hh][c] = B[(long)(h0 + hh) * NH + j0 + c];
        }
        __syncthreads();
        for (int hh = 0; hh < 32; ++hh) {
            float4 av  = *(const float4*)&AtT[hh][r4];
            float4 bv0 = *(const float4*)&Bt[hh][c8];
            float4 bv1 = *(const float4*)&Bt[hh][c8 + 4];
            float a[4] = {av.x, av.y, av.z, av.w};
            float bb[8] = {bv0.x, bv0.y, bv0.z, bv0.w, bv1.x, bv1.y, bv1.z, bv1.w};
            #pragma unroll
            for (int rr = 0; rr < 4; ++rr)
                #pragma unroll
                for (int cc = 0; cc < 8; ++cc) acc[rr][cc] += a[rr] * bb[cc];
        }
        __syncthreads();
    }
    float part[4] = {0.f, 0.f, 0.f, 0.f};
    #pragma unroll
    for (int rr = 0; rr < 4; ++rr)
        #pragma unroll
        for (int cc = 0; cc < 8; ++cc)
            part[rr] += tanh_fast(acc[rr][cc] + wht_s[c8 + cc]) * we_s[c8 + cc];
    #pragma unroll
    for (int rr = 0; rr < 4; ++rr)
        atomicAdd(&sred[r4 + rr], part[rr]);
    __syncthreads();
    if (t < 64)
        atomicAdd(&scores[(((k << 5) + b) << 9) + s0 + t], sred[t]);
}

// Shuffle-based softmax + head-combine + argmax + xT build. grid 32.
__global__ void softmax_kernel(const float* __restrict__ scores,
                               const float* __restrict__ headw_W, const float* __restrict__ headw_b,
                               const float* __restrict__ text,
                               const float* __restrict__ q_f32,
                               float* __restrict__ xT, float* __restrict__ out_prob, int hop)
{
    __shared__ float sc[NK][NS];
    __shared__ float cred[4];
    __shared__ float cval[4];
    __shared__ int   cidx[4];
    int b = blockIdx.x, t = threadIdx.x;
    int wave = t >> 6, lane = t & 63;
    for (int i = t; i < NK * NS; i += 256) {
        int k = i >> 9, s = i & 511;
        sc[k][s] = scores[((k*NB + b) << 9) + s];
    }
    __syncthreads();
    float fac[NK];
    for (int k = 0; k < NK; ++k) {
        float v0 = sc[k][t], v1 = sc[k][t + 256];
        float m = fmaxf(v0, v1);
        #pragma unroll
        for (int o = 32; o > 0; o >>= 1) m = fmaxf(m, __shfl_xor(m, o));
        if (lane == 0) cred[wave] = m;
        __syncthreads();
        float mx = fmaxf(fmaxf(cred[0], cred[1]), fmaxf(cred[2], cred[3]));
        __syncthreads();
        float e0 = __expf(v0 - mx), e1 = __expf(v1 - mx);
        sc[k][t] = e0; sc[k][t + 256] = e1;
        float sm = e0 + e1;
        #pragma unroll
        for (int o = 32; o > 0; o >>= 1) sm += __shfl_xor(sm, o);
        if (lane == 0) cred[wave] = sm;
        __syncthreads();
        fac[k] = headw_W[k] / (cred[0] + cred[1] + cred[2] + cred[3]);
        __syncthreads();
    }
    float hwb = headw_b[0];
    float a0 = hwb, a1 = hwb;
    for (int k = 0; k < NK; ++k) { a0 += sc[k][t] * fac[k]; a1 += sc[k][t + 256] * fac[k]; }
    float ss = a0*a0 + a1*a1;
    #pragma unroll
    for (int o = 32; o > 0; o >>= 1) ss += __shfl_xor(ss, o);
    float bv; int bi;
    if (a0 >= a1) { bv = a0; bi = t; } else { bv = a1; bi = t + 256; }
    #pragma unroll
    for (int o = 1; o < 64; o <<= 1) {
        float ov = __shfl_xor(bv, o);
        int   oi = __shfl_xor(bi, o);
        if (ov > bv || (ov == bv && oi < bi)) { bv = ov; bi = oi; }
    }
    if (lane == 0) { cred[wave] = ss; cval[wave] = bv; cidx[wave] = bi; }
    __syncthreads();
    float scale = sqrtf(cred[0] + cred[1] + cred[2] + cred[3]);
    float mbv = cval[0]; int mbi = cidx[0];
    #pragma unroll
    for (int w = 1; w < 4; ++w)
        if (cval[w] > mbv || (cval[w] == mbv && cidx[w] < mbi)) { mbv = cval[w]; mbi = cidx[w]; }
    int idx = mbi;
    if (hop == 0) {
        out_prob[(b << 9) + t]       = a0 / scale;
        out_prob[(b << 9) + t + 256] = a1 / scale;
    }
    const float* trow = text + (long)(b * NS + idx) * NH;
    for (int i = t; i < NH; i += 256) {
        xT[i * NB + b]        = q_f32[b*NH + i];
        xT[(NH + i) * NB + b] = trow[i];
    }
}

// GRU matvec partials: grid (36 j-tiles, 9 chunks: 6 sx + 3 sh); atomicAdd.
__global__ __launch_bounds__(256) void gru_mm3_kernel(
    const float* __restrict__ Wih, const float* __restrict__ Whh,
    const float* __restrict__ xT, const float* __restrict__ hT,
    float* __restrict__ sx, float* __restrict__ sh)
{
    __shared__ float xs[8192];
    int t = threadIdx.x;
    int tj = t & 63, tq = t >> 6;
    int j = blockIdx.x * 64 + tj;
    int cgi = blockIdx.y;
    const float* W; const float* src; float* dst; int c;
    if (cgi < 6) { W = Wih; src = xT; dst = sx; c = cgi; }
    else         { W = Whh; src = hT; dst = sh; c = cgi - 6; }
    for (int idx = t; idx < 8192; idx += 256) xs[idx] = src[c * 8192 + idx];
    __syncthreads();
    float acc[8];
    #pragma unroll
    for (int bq = 0; bq < 8; ++bq) acc[bq] = 0.f;
    #pragma unroll 8
    for (int ii = 0; ii < 256; ++ii) {
        float w = W[(long)(c * 256 + ii) * H3 + j];
        #pragma unroll
        for (int bq = 0; bq < 8; ++bq) acc[bq] += xs[ii * 32 + tq * 8 + bq] * w;
    }
    #pragma unroll
    for (int bq = 0; bq < 8; ++bq)
        atomicAdd(&dst[(long)(tq * 8 + bq) * H3 + j], acc[bq]);
}

// Gate + h/q update; re-zeroes sx/sh for the next hop after reading.
__global__ void gate_kernel(const float* __restrict__ bih, const float* __restrict__ bhh,
                            float* __restrict__ sx, float* __restrict__ sh,
                            float* __restrict__ hT, float* __restrict__ q_f32,
                            float* __restrict__ out_h, int hop)
{
    int gid = blockIdx.x * 256 + threadIdx.x;
    int b = gid / NH, j = gid % NH;
    float xr = bih[j]        + sx[b*H3 + j];
    float xz = bih[NH + j]   + sx[b*H3 + NH + j];
    float xn = bih[1536 + j] + sx[b*H3 + 1536 + j];
    float hr = bhh[j]        + sh[b*H3 + j];
    float hz = bhh[NH + j]   + sh[b*H3 + NH + j];
    float hn = bhh[1536 + j] + sh[b*H3 + 1536 + j];
    sx[b*H3 + j] = 0.f; sx[b*H3 + NH + j] = 0.f; sx[b*H3 + 1536 + j] = 0.f;
    sh[b*H3 + j] = 0.f; sh[b*H3 + NH + j] = 0.f; sh[b*H3 + 1536 + j] = 0.f;
    float r = sig_fast(xr + hr);
    float z = sig_fast(xz + hz);
    float n = tanh_fast(xn + r * hn);
    float hp = hT[j * NB + b];
    float hnew = (1.f - z) * n + z * hp;
    hT[j * NB + b] = hnew;
    q_f32[gid] = hnew;
    out_h[(long)(b * 3 + hop) * NH + j] = hnew;
}

// ---------------------------------------------------------------------------
extern "C" void kernel_launch(void* const* d_in, const int* in_sizes, int n_in,
                              void* d_out, int out_size, void* d_ws, size_t ws_size,
                              hipStream_t stream)
{
    const float* question = (const float*)d_in[0];
    const float* text     = (const float*)d_in[1];
    const float* pw_W     = (const float*)d_in[2];
    const float* pw_b     = (const float*)d_in[3];
    const float* Ws_W     = (const float*)d_in[4];
    const float* Ws_b     = (const float*)d_in[5];
    const float* Wt_W     = (const float*)d_in[6];
    const float* Wt_b     = (const float*)d_in[7];
    const float* We_W     = (const float*)d_in[8];
    const float* We_b     = (const float*)d_in[9];
    const float* headw_W  = (const float*)d_in[10];
    const float* headw_b  = (const float*)d_in[11];
    const float* Wih      = (const float*)d_in[12];
    const float* Whh      = (const float*)d_in[13];
    const float* bih      = (const float*)d_in[14];
    const float* bhh      = (const float*)d_in[15];

    char* ws = (char*)d_ws;
    float* comb   = (float*)(ws + 0);
    float* combB  = (float*)(ws + 9437184);
    float* W_ht   = (float*)(ws + 9449472);
    float* scores = (float*)(ws + 9842688);
    float* q_f32  = (float*)(ws + 10104832);
    float* hT     = (float*)(ws + 10203136);
    float* xT     = (float*)(ws + 10301440);
    float* sx     = (float*)(ws + 10498048);
    float* sh     = (float*)(ws + 10792960);
    u16*   combTH = (u16*)  (ws + 11087872);
    u16*   combTL = (u16*)  (ws + 15806464);
    u16*   TP     = (u16*)  (ws + 20525056);
    u16*   textH  = (u16*)  (ws + 121188352);
    // prep scratch overlaid on TP region (dead before tp_gemm runs):
    u16*   WsTH   = (u16*)  (ws + 20525056);
    u16*   pwH    = (u16*)  (ws + 29962240);

    int nstore = 0;
    if (ws_size >= (size_t)70856704) {
        long avail = (long)ws_size - 20525056L;
        nstore = (int)(avail / 25165824L);
        if (nstore > NK) nstore = NK;
    }
    const int tier = (nstore >= 1) ? 3
                   : (ws_size >= (size_t)20525056) ? 1 : 0;
    const bool haveTextH = (tier == 3) && (nstore == NK)
                        && (ws_size >= (size_t)146354176);

    float* out_prob = (float*)d_out;
    float* out_h    = (float*)d_out + NB * NS;

    const int prepGrid = haveTextH ? 17968 : (tier >= 2 ? 5680 : 1072);
    prep_kernel<<<prepGrid, 256, 0, stream>>>(
        Ws_W, pw_b, Ws_b, combB, question, q_f32, hT, sx, sh, We_b, scores,
        pw_W, WsTH, pwH, text, textH,
        tier >= 3 ? 2 : tier, haveTextH ? 1 : 0);

    if (tier == 3) {
        comb_mfma_kernel<<<dim3(6, 6, 4), 256, 0, stream>>>(WsTH, pwH,
                                                            combTH, combTL);
        // scratch dead from here; TP overwrites it.
        if (haveTextH) {
            tp_gemm_kernel<1><<<dim3(128, 6, nstore), 256, 0, stream>>>(
                text, textH, combTH, combTL, TP);
        } else {
            tp_gemm_kernel<0><<<dim3(128, 6, nstore), 256, 0, stream>>>(
                text, nullptr, combTH, combTL, TP);
        }
    } else {
        comb_valu_kernel<<<dim3(12, 6, 4), 256, 0, stream>>>(pw_W, Ws_W, comb);
        if (tier == 1)
            split_combT_kernel<<<2304, 256, 0, stream>>>(comb, combTH, combTL);
    }

    for (int hop = 0; hop < 3; ++hop) {
        wht2_kernel<<<384, 256, 0, stream>>>(q_f32, Wt_W, combB, Wt_b, W_ht);
        if (tier == 3) {
            score_pass_kernel<<<dim3(8, 32, nstore), 256, 0, stream>>>(
                TP, W_ht, We_W, We_b, scores);
            if (nstore < NK) {
                if (hop > 0)
                    init_scores_kernel<<<(NK - nstore) * 64, 256, 0, stream>>>(
                        We_b, scores, nstore);
                fused_scores_mfma<0><<<dim3(128, 6, NK - nstore), 256, 0, stream>>>(
                    text, nullptr, nullptr, combTH, combTL, W_ht, We_W,
                    scores, nstore);
            }
        } else if (tier == 1) {
            init_scores_kernel<<<256, 256, 0, stream>>>(We_b, scores, 0);
            fused_scores_mfma<0><<<dim3(128, 6, 4), 256, 0, stream>>>(
                text, nullptr, nullptr, combTH, combTL, W_ht, We_W, scores, 0);
        } else {
            init_scores_kernel<<<256, 256, 0, stream>>>(We_b, scores, 0);
            fused_scores_valu<<<dim3(256, 6, 4), 256, 0, stream>>>(
                text, comb, W_ht, We_W, scores);
        }
        softmax_kernel<<<32, 256, 0, stream>>>(scores, headw_W, headw_b, text,
                                               q_f32, xT, out_prob, hop);
        gru_mm3_kernel<<<dim3(36, 9), 256, 0, stream>>>(Wih, Whh, xT, hT, sx, sh);
        gate_kernel<<<96, 256, 0, stream>>>(bih, bhh, sx, sh, hT, q_f32, out_h, hop);
    }
}